// Round 8
// baseline (1152.821 us; speedup 1.0000x reference)
//
#include <hip/hip_runtime.h>
#include <hip/hip_fp16.h>

// fixed-point scale for weighted-degree accumulation (2^25)
#define FIX 33554432.0f
#define FIXINV (1.0f / 33554432.0f)

typedef unsigned long long ull;

// edges per block for edge-walk kernels (count_deg_k and part1_k MUST match:
// identical grid shape + blockIdx&7 class => per-(bucket,class) counts line up)
#define EB 1024
// bucket = 128 dst nodes
#define BSH 7
#define BNODES 128
#define PAD 41  // LDS row stride (odd multiplier -> bank spread)

// ---------------- zero the 8 privatized degcnt copies ----------------
__global__ void zero_k(ull* degcnt8, long total) {
    long i = (long)blockIdx.x * blockDim.x + threadIdx.x;
    if (i < total) degcnt8[i] = 0ULL;
}

// ---------------- per-edge: packed 64-bit atomic into XCD-class-local copy ----------------
__global__ void count_deg_k(const int* __restrict__ dst, const float* __restrict__ ew,
                            ull* degcnt8, int n, int e) {
    ull* my = degcnt8 + (long)(blockIdx.x & 7) * n;
    int base = blockIdx.x * EB + threadIdx.x * 4;
    if (base + 3 < e) {
        int4 d4 = *reinterpret_cast<const int4*>(dst + base);
        float4 e4 = *reinterpret_cast<const float4*>(ew + base);
        atomicAdd(&my[d4.x], (1ULL << 32) | (ull)__float2uint_rn(e4.x * FIX));
        atomicAdd(&my[d4.y], (1ULL << 32) | (ull)__float2uint_rn(e4.y * FIX));
        atomicAdd(&my[d4.z], (1ULL << 32) | (ull)__float2uint_rn(e4.z * FIX));
        atomicAdd(&my[d4.w], (1ULL << 32) | (ull)__float2uint_rn(e4.w * FIX));
    } else {
        for (int i = base; i < e && i < base + 4; ++i)
            atomicAdd(&my[dst[i]], (1ULL << 32) | (ull)__float2uint_rn(ew[i] * FIX));
    }
}

// ---------------- reduce 8 copies; add self-loop; emit dinv ----------------
__global__ void dinv_k(const ull* __restrict__ degcnt8, float* __restrict__ dinv, int n) {
    int i = blockIdx.x * blockDim.x + threadIdx.x;
    if (i < n) {
        ull v = (ull)(1u << 25);  // self-loop weight 1.0 fixed-point
#pragma unroll
        for (int c = 0; c < 8; ++c) v += degcnt8[(long)c * n + i];
        float d = (float)(unsigned)(v & 0xffffffffu) * FIXINV;  // >= 1.0 always
        dinv[i] = rsqrtf(d);
    }
}

// ---------------- per-(bucket,class) record counts ----------------
__global__ void bxsum_k(const ull* __restrict__ degcnt8, int* __restrict__ bxsum, int n) {
    __shared__ int lds[BNODES];
    int b = blockIdx.x;
    int node = b * BNODES + threadIdx.x;
#pragma unroll
    for (int x = 0; x < 8; ++x) {
        lds[threadIdx.x] = (node < n) ? (int)(degcnt8[(long)x * n + node] >> 32) : 0;
        __syncthreads();
        for (int off = BNODES / 2; off > 0; off >>= 1) {
            if (threadIdx.x < off) lds[threadIdx.x] += lds[threadIdx.x + off];
            __syncthreads();
        }
        if (threadIdx.x == 0) bxsum[b * 8 + x] = lds[0];
        __syncthreads();
    }
}

// ---------------- exclusive scan of M=(NB*8) counts -> padded cursors + bases ----------------
__global__ void scanbx_k(const int* __restrict__ bxsum, int* __restrict__ bxcur,
                         int* __restrict__ bxbase, int M, int e) {
    __shared__ int lds[256];
    int per = (M + 255) / 256;
    int s = 0;
    for (int j = 0; j < per; ++j) {
        int idx = threadIdx.x * per + j;
        if (idx < M) s += bxsum[idx];
    }
    lds[threadIdx.x] = s;
    __syncthreads();
    for (int off = 1; off < 256; off <<= 1) {
        int v = (threadIdx.x >= off) ? lds[threadIdx.x - off] : 0;
        __syncthreads();
        lds[threadIdx.x] += v;
        __syncthreads();
    }
    int run = lds[threadIdx.x] - s;
    for (int j = 0; j < per; ++j) {
        int idx = threadIdx.x * per + j;
        if (idx < M) {
            bxcur[idx * 16] = run;
            bxbase[idx * 16] = run;
            run += bxsum[idx];
        }
    }
    if (threadIdx.x == 255) bxbase[M * 16] = e;  // sentinel
}

// ---------------- phase 1: bucket-partition edges, packed 8B records ----------------
// rec = wbits[59:28] | src[27:8] | (dst&127)[7:0]   (src < 2^20)
__global__ void part1_k(const int* __restrict__ src, const int* __restrict__ dst,
                        const float* __restrict__ ew, const float* __restrict__ dinv,
                        int* bxcur, ull* __restrict__ tmp, int e) {
    int x = blockIdx.x & 7;
    int base = blockIdx.x * EB + threadIdx.x * 4;
    if (base + 3 < e) {
        int4 s4 = *reinterpret_cast<const int4*>(src + base);
        int4 d4 = *reinterpret_cast<const int4*>(dst + base);
        float4 e4 = *reinterpret_cast<const float4*>(ew + base);
        int s[4] = {s4.x, s4.y, s4.z, s4.w};
        int d[4] = {d4.x, d4.y, d4.z, d4.w};
        float ev[4] = {e4.x, e4.y, e4.z, e4.w};
        ull rec[4];
        int slot[4];
#pragma unroll
        for (int j = 0; j < 4; ++j) {
            float wv = dinv[s[j]] * ev[j];
            rec[j] = ((ull)__float_as_uint(wv) << 28) | ((ull)(unsigned)s[j] << 8) |
                     (ull)(unsigned)(d[j] & (BNODES - 1));
        }
#pragma unroll
        for (int j = 0; j < 4; ++j)
            slot[j] = atomicAdd(&bxcur[((d[j] >> BSH) * 8 + x) * 16], 1);
#pragma unroll
        for (int j = 0; j < 4; ++j) tmp[slot[j]] = rec[j];
    } else {
        for (int i = base; i < e && i < base + 4; ++i) {
            int s = src[i], d = dst[i];
            float wv = dinv[s] * ew[i];
            int slot = atomicAdd(&bxcur[((d >> BSH) * 8 + x) * 16], 1);
            tmp[slot] = ((ull)__float_as_uint(wv) << 28) | ((ull)(unsigned)s << 8) |
                        (ull)(unsigned)(d & (BNODES - 1));
        }
    }
}

// ---------------- f32 -> fp16 convert (vectorized) ----------------
__global__ void tohalf_k(const float4* __restrict__ in, __half2* __restrict__ out, long n4) {
    long i = (long)blockIdx.x * blockDim.x + threadIdx.x;
    if (i < n4) {
        float4 v = in[i];
        out[2 * i] = __floats2half2_rn(v.x, v.y);
        out[2 * i + 1] = __floats2half2_rn(v.z, v.w);
    }
}

// ---------------- dense linear: y[n,C] = x[n,K] @ W[K,C] ----------------
template <int K, int C, bool BIAS_RELU, bool DUAL16>
__global__ void linear_k(const float* __restrict__ x, const float* __restrict__ W,
                         const float* __restrict__ b, float* __restrict__ y,
                         __half* __restrict__ y16, int n) {
    __shared__ float Ws[K * C];
    for (int i = threadIdx.x; i < K * C; i += blockDim.x) Ws[i] = W[i];
    __syncthreads();
    long gid = (long)blockIdx.x * blockDim.x + threadIdx.x;
    int node = (int)(gid / C);
    int c = (int)(gid % C);
    if (node >= n) return;
    const float* xr = x + (long)node * K;
    float acc = 0.0f;
#pragma unroll
    for (int k = 0; k < K; ++k) acc = fmaf(xr[k], Ws[k * C + c], acc);
    if (BIAS_RELU) acc = fmaxf(acc + b[c], 0.0f);
    y[gid] = acc;
    if (DUAL16) y16[gid] = __float2half(acc);
}

__device__ inline float2 h2f(unsigned u) {
    __half2 h = *reinterpret_cast<__half2*>(&u);
    return __half22float2(h);
}

// ---------------- fused bucket aggregation: LDS accumulator, no CSR ----------------
// out[d] = dinv[d] * sum_rec(w' * feat16[src]) + dinv[d]^2 * selfF[d] (+ b)
template <bool ADD_BIAS>
__global__ void agg_k(const ull* __restrict__ tmp, const int* __restrict__ bxbase,
                      const __half* __restrict__ feat16, const float* __restrict__ selfF,
                      const float* __restrict__ dinv, const float* __restrict__ bias,
                      float* __restrict__ outF, int n) {
    __shared__ float acc[BNODES * PAD];
    int b = blockIdx.x;
    for (int i = threadIdx.x; i < BNODES * PAD; i += 256) acc[i] = 0.0f;
    __syncthreads();
    int beg = bxbase[(b * 8) * 16];
    int end = bxbase[((b + 1) * 8) * 16];
    for (int i = beg + threadIdx.x; i < end; i += 256) {
        ull rec = tmp[i];
        int dlo = (int)(rec & (BNODES - 1));
        int s = (int)((rec >> 8) & 0xFFFFF);
        float w = __uint_as_float((unsigned)(rec >> 28));
        const uint4* row = reinterpret_cast<const uint4*>(feat16 + (long)s * 40);
        float* a = acc + dlo * PAD;
        uint4 q0 = row[0], q1 = row[1], q2 = row[2], q3 = row[3], q4 = row[4];
        unsigned qs[20] = {q0.x, q0.y, q0.z, q0.w, q1.x, q1.y, q1.z, q1.w,
                           q2.x, q2.y, q2.z, q2.w, q3.x, q3.y, q3.z, q3.w,
                           q4.x, q4.y, q4.z, q4.w};
#pragma unroll
        for (int c = 0; c < 20; ++c) {
            float2 v = h2f(qs[c]);
            atomicAdd(&a[2 * c], w * v.x);
            atomicAdd(&a[2 * c + 1], w * v.y);
        }
    }
    __syncthreads();
    int nlo = b * BNODES;
    for (int i = threadIdx.x; i < BNODES * 40; i += 256) {
        int l = i / 40;
        int c = i - l * 40;
        int node = nlo + l;
        if (node < n) {
            float di = dinv[node];
            float r = di * acc[l * PAD + c] + di * di * selfF[(long)nlo * 40 + i];
            if (ADD_BIAS) r += bias[c];
            outF[(long)nlo * 40 + i] = r;
        }
    }
}

extern "C" void kernel_launch(void* const* d_in, const int* in_sizes, int n_in,
                              void* d_out, int out_size, void* d_ws, size_t ws_size,
                              hipStream_t stream) {
    const float* x = (const float*)d_in[0];
    const int* ei = (const int*)d_in[1];
    const float* ew = (const float*)d_in[2];
    const float* W1 = (const float*)d_in[3];
    const float* b1 = (const float*)d_in[4];
    const float* W2 = (const float*)d_in[5];
    const float* b2 = (const float*)d_in[6];
    float* out = (float*)d_out;

    const int n = in_sizes[0] / 40;   // 100000
    const int e = in_sizes[2];        // 1600000
    const int* srcp = ei;
    const int* dstp = ei + e;
    const int NB = (n + BNODES - 1) >> BSH;  // buckets of 128 dst nodes
    const int NB8 = NB * 8;

    // ws layout (4B units):
    // tmp[e] (8B recs) | dinv[n] | bxcur[NB8*16] | bxbase[(NB8+1)*16] | bxsum[NB8] |
    // agg1/xl2_32[n*40] | h[n*64] | sh16 (40n halves, shared by x16 & xl2_16)
    // degcnt8 (8n ull = 16n floats) overlays h (dead before linear1 writes h)
    ull* tmp = (ull*)d_ws;
    float* dinv = (float*)(tmp + e);
    int* bxcur = (int*)(dinv + n);
    int* bxbase = bxcur + NB8 * 16;
    int* bxsum = bxbase + (NB8 + 1) * 16;
    float* agg1 = (float*)(bxsum + NB8);
    float* h = agg1 + (long)n * 40;
    __half* sh16 = (__half*)(h + (long)n * 64);
    float* xl2_32 = agg1;                 // overlay: agg1 dead after linear1
    ull* degcnt8 = (ull*)(((uintptr_t)h + 7) & ~(uintptr_t)7);

    const int B = 256;
    auto cdiv = [](long a, long b) { return (int)((a + b - 1) / b); };
    const int egrid = cdiv(e, EB);  // shared by count_deg_k / part1_k (class match!)

    // ---- degree + bucket cursors ----
    zero_k<<<cdiv((long)n * 8, B), B, 0, stream>>>(degcnt8, (long)n * 8);
    count_deg_k<<<egrid, B, 0, stream>>>(dstp, ew, degcnt8, n, e);
    dinv_k<<<cdiv(n, B), B, 0, stream>>>(degcnt8, dinv, n);
    bxsum_k<<<NB, BNODES, 0, stream>>>(degcnt8, bxsum, n);
    scanbx_k<<<1, 256, 0, stream>>>(bxsum, bxcur, bxbase, NB8, e);
    part1_k<<<egrid, B, 0, stream>>>(srcp, dstp, ew, dinv, bxcur, tmp, e);

    // ---- x -> fp16 (edge operand for layer 1) ----
    tohalf_k<<<cdiv((long)n * 10, B), B, 0, stream>>>((const float4*)x, (__half2*)sh16, (long)n * 10);

    // ---- layer 1: agg1 = A_norm @ x (fused bucket scatter), h = relu(agg1 @ W1 + b1) ----
    agg_k<false><<<NB, 256, 0, stream>>>(tmp, bxbase, sh16, x, dinv, nullptr, agg1, n);
    linear_k<40, 64, true, false><<<cdiv((long)n * 64, B), B, 0, stream>>>(agg1, W1, b1, h, nullptr, n);

    // ---- layer 2: xl2 = h @ W2 (f32 + fp16), out = A_norm @ xl2 + b2 ----
    linear_k<64, 40, false, true><<<cdiv((long)n * 40, B), B, 0, stream>>>(h, W2, nullptr, xl2_32, sh16, n);
    agg_k<true><<<NB, 256, 0, stream>>>(tmp, bxbase, sh16, xl2_32, dinv, b2, out, n);
}

// Round 9
// 451.651 us; speedup vs baseline: 2.5525x; 2.5525x over previous
//
#include <hip/hip_runtime.h>
#include <hip/hip_fp16.h>

// fixed-point scale for weighted-degree accumulation (2^25)
#define FIX 33554432.0f
#define FIXINV (1.0f / 33554432.0f)

typedef unsigned long long ull;

// edges per block for edge-walk kernels (count_deg_k and part1_k MUST match:
// identical grid shape + blockIdx&7 class => per-(bucket,class) counts line up)
#define EB 1024
// coarse bucket = 1024 dst nodes
#define CSH 10
#define CNODES 1024

// ---------------- zero the 8 privatized degcnt copies ----------------
__global__ void zero_k(ull* degcnt8, long total) {
    long i = (long)blockIdx.x * blockDim.x + threadIdx.x;
    if (i < total) degcnt8[i] = 0ULL;
}

// ---------------- per-edge: packed 64-bit atomic into XCD-class-local copy ----------------
__global__ void count_deg_k(const int* __restrict__ dst, const float* __restrict__ ew,
                            ull* degcnt8, int n, int e) {
    ull* my = degcnt8 + (long)(blockIdx.x & 7) * n;
    int base = blockIdx.x * EB + threadIdx.x * 4;
    if (base + 3 < e) {
        int4 d4 = *reinterpret_cast<const int4*>(dst + base);
        float4 e4 = *reinterpret_cast<const float4*>(ew + base);
        atomicAdd(&my[d4.x], (1ULL << 32) | (ull)__float2uint_rn(e4.x * FIX));
        atomicAdd(&my[d4.y], (1ULL << 32) | (ull)__float2uint_rn(e4.y * FIX));
        atomicAdd(&my[d4.z], (1ULL << 32) | (ull)__float2uint_rn(e4.z * FIX));
        atomicAdd(&my[d4.w], (1ULL << 32) | (ull)__float2uint_rn(e4.w * FIX));
    } else {
        for (int i = base; i < e && i < base + 4; ++i)
            atomicAdd(&my[dst[i]], (1ULL << 32) | (ull)__float2uint_rn(ew[i] * FIX));
    }
}

// ---------------- reduce 8 copies; add self-loop; emit dinv + cnt ----------------
__global__ void dinv_k(const ull* __restrict__ degcnt8, float* __restrict__ dinv,
                       int* __restrict__ cnt, int n) {
    int i = blockIdx.x * blockDim.x + threadIdx.x;
    if (i < n) {
        ull v = (ull)(1u << 25);  // self-loop weight 1.0 fixed-point
#pragma unroll
        for (int c = 0; c < 8; ++c) v += degcnt8[(long)c * n + i];
        cnt[i] = (int)(v >> 32);
        float d = (float)(unsigned)(v & 0xffffffffu) * FIXINV;  // >= 1.0 always
        dinv[i] = rsqrtf(d);
    }
}

// ---------------- scan step 1: per-2048-chunk exclusive scan ----------------
__global__ void scan1_k(const int* __restrict__ cnt, int* __restrict__ excl,
                        int* __restrict__ bsum, int n) {
    __shared__ int lds[256];
    int base = blockIdx.x * 2048;
    int pre[8];
    int tsum = 0;
#pragma unroll
    for (int j = 0; j < 8; ++j) {
        int idx = base + threadIdx.x * 8 + j;
        int v = (idx < n) ? cnt[idx] : 0;
        pre[j] = tsum;
        tsum += v;
    }
    lds[threadIdx.x] = tsum;
    __syncthreads();
    for (int off = 1; off < 256; off <<= 1) {
        int v = (threadIdx.x >= off) ? lds[threadIdx.x - off] : 0;
        __syncthreads();
        lds[threadIdx.x] += v;
        __syncthreads();
    }
    int texcl = lds[threadIdx.x] - tsum;
    if (threadIdx.x == 255) bsum[blockIdx.x] = lds[255];
#pragma unroll
    for (int j = 0; j < 8; ++j) {
        int idx = base + threadIdx.x * 8 + j;
        if (idx < n) excl[idx] = texcl + pre[j];
    }
}

// ---------------- scan step 2: serial exclusive scan of block sums ----------------
__global__ void scan2_k(int* bsum, int nb, int* rowptr_end, int e) {
    if (threadIdx.x == 0 && blockIdx.x == 0) {
        int run = 0;
        for (int i = 0; i < nb; ++i) {
            int v = bsum[i];
            bsum[i] = run;
            run += v;
        }
        *rowptr_end = e;
    }
}

// ---------------- scan step 3: add block offsets -> final rowptr ----------------
__global__ void scan3_k(int* __restrict__ rowptr, const int* __restrict__ bsum, int n) {
    int i = blockIdx.x * blockDim.x + threadIdx.x;
    if (i < n) rowptr[i] += bsum[i >> 11];
}

// ---------------- per-(coarse bucket, class) record counts ----------------
__global__ void cbsum_k(const ull* __restrict__ degcnt8, int* __restrict__ cbsum, int n) {
    __shared__ int lds[256];
    int b = blockIdx.x;
#pragma unroll
    for (int x = 0; x < 8; ++x) {
        int s = 0;
#pragma unroll
        for (int j = 0; j < CNODES / 256; ++j) {
            int node = b * CNODES + j * 256 + threadIdx.x;
            if (node < n) s += (int)(degcnt8[(long)x * n + node] >> 32);
        }
        lds[threadIdx.x] = s;
        __syncthreads();
        for (int off = 128; off > 0; off >>= 1) {
            if (threadIdx.x < off) lds[threadIdx.x] += lds[threadIdx.x + off];
            __syncthreads();
        }
        if (threadIdx.x == 0) cbsum[b * 8 + x] = lds[0];
        __syncthreads();
    }
}

// ---------------- exclusive scan of M counts -> padded cursors + bases ----------------
__global__ void scancb_k(const int* __restrict__ cbsum, int* __restrict__ cbcur,
                         int* __restrict__ cbase, int M, int e) {
    __shared__ int lds[256];
    int per = (M + 255) / 256;
    int s = 0;
    for (int j = 0; j < per; ++j) {
        int idx = threadIdx.x * per + j;
        if (idx < M) s += cbsum[idx];
    }
    lds[threadIdx.x] = s;
    __syncthreads();
    for (int off = 1; off < 256; off <<= 1) {
        int v = (threadIdx.x >= off) ? lds[threadIdx.x - off] : 0;
        __syncthreads();
        lds[threadIdx.x] += v;
        __syncthreads();
    }
    int run = lds[threadIdx.x] - s;
    for (int j = 0; j < per; ++j) {
        int idx = threadIdx.x * per + j;
        if (idx < M) {
            cbcur[idx * 16] = run;
            cbase[idx * 16] = run;
            run += cbsum[idx];
        }
    }
    if (threadIdx.x == 255) cbase[M * 16] = e;  // sentinel
}

// ---------------- phase 1: coarse-bucket partition, packed 8B records ----------------
// rec = wbits[58:27] | src[26:10] | (dst&1023)[9:0]
__global__ void part1_k(const int* __restrict__ src, const int* __restrict__ dst,
                        const float* __restrict__ ew, const float* __restrict__ dinv,
                        int* cbcur, ull* __restrict__ tmp, int e) {
    int x = blockIdx.x & 7;
    int base = blockIdx.x * EB + threadIdx.x * 4;
    if (base + 3 < e) {
        int4 s4 = *reinterpret_cast<const int4*>(src + base);
        int4 d4 = *reinterpret_cast<const int4*>(dst + base);
        float4 e4 = *reinterpret_cast<const float4*>(ew + base);
        int s[4] = {s4.x, s4.y, s4.z, s4.w};
        int d[4] = {d4.x, d4.y, d4.z, d4.w};
        float ev[4] = {e4.x, e4.y, e4.z, e4.w};
        ull rec[4];
        int slot[4];
#pragma unroll
        for (int j = 0; j < 4; ++j) {
            float wv = dinv[s[j]] * ev[j];
            rec[j] = ((ull)__float_as_uint(wv) << 27) | ((ull)(unsigned)s[j] << 10) |
                     (ull)(unsigned)(d[j] & (CNODES - 1));
        }
#pragma unroll
        for (int j = 0; j < 4; ++j)
            slot[j] = atomicAdd(&cbcur[((d[j] >> CSH) * 8 + x) * 16], 1);
#pragma unroll
        for (int j = 0; j < 4; ++j) tmp[slot[j]] = rec[j];
    } else {
        for (int i = base; i < e && i < base + 4; ++i) {
            int s = src[i], d = dst[i];
            float wv = dinv[s] * ew[i];
            int slot = atomicAdd(&cbcur[((d >> CSH) * 8 + x) * 16], 1);
            tmp[slot] = ((ull)__float_as_uint(wv) << 27) | ((ull)(unsigned)s << 10) |
                        (ull)(unsigned)(d & (CNODES - 1));
        }
    }
}

// ---------------- phase 2: coarse bucket -> node-sorted packed CSR (LDS cursors) ----------------
__global__ __launch_bounds__(1024) void part2_k(const ull* __restrict__ tmp,
                                                const int* __restrict__ cbase,
                                                const int* __restrict__ rowptr,
                                                uint2* __restrict__ csr, int n) {
    __shared__ int cur[CNODES];
    int b = blockIdx.x;
    int nlo = b * CNODES;
    for (int i = threadIdx.x; i < CNODES; i += 1024) {
        int node = nlo + i;
        cur[i] = (node < n) ? rowptr[node] : 0;
    }
    __syncthreads();
    int beg = cbase[(b * 8) * 16];
    int end = cbase[((b + 1) * 8) * 16];
    for (int i = beg + threadIdx.x; i < end; i += 1024) {
        ull rec = tmp[i];
        int dlo = (int)(rec & (CNODES - 1));
        unsigned s = (unsigned)((rec >> CSH) & 0x1FFFF);
        unsigned wb = (unsigned)(rec >> 27);
        int slot = atomicAdd(&cur[dlo], 1);
        csr[slot] = make_uint2(s, wb);
    }
}

// ---------------- f32 -> fp16, rows padded to 64 halves (128B-aligned rows) ----------------
__global__ void tohalf_k(const float* __restrict__ x, __half* __restrict__ out, int n) {
    long gid = (long)blockIdx.x * blockDim.x + threadIdx.x;
    if (gid >= (long)n * 5) return;
    int row = (int)(gid / 5), c = (int)(gid % 5);
    const float4* src = reinterpret_cast<const float4*>(x + (long)row * 40 + c * 8);
    float4 a = src[0], b = src[1];
    __half2* dst = reinterpret_cast<__half2*>(out + (long)row * 64 + c * 8);
    dst[0] = __floats2half2_rn(a.x, a.y);
    dst[1] = __floats2half2_rn(a.z, a.w);
    dst[2] = __floats2half2_rn(b.x, b.y);
    dst[3] = __floats2half2_rn(b.z, b.w);
}

// ---------------- dense linear: y[n,C] = x[n,K] @ W[K,C] ----------------
// DUAL16 also emits fp16 copy at row stride 64 (padded table)
template <int K, int C, bool BIAS_RELU, bool DUAL16>
__global__ void linear_k(const float* __restrict__ x, const float* __restrict__ W,
                         const float* __restrict__ b, float* __restrict__ y,
                         __half* __restrict__ y16, int n) {
    __shared__ float Ws[K * C];
    for (int i = threadIdx.x; i < K * C; i += blockDim.x) Ws[i] = W[i];
    __syncthreads();
    long gid = (long)blockIdx.x * blockDim.x + threadIdx.x;
    int node = (int)(gid / C);
    int c = (int)(gid % C);
    if (node >= n) return;
    const float* xr = x + (long)node * K;
    float acc = 0.0f;
#pragma unroll
    for (int k = 0; k < K; ++k) acc = fmaf(xr[k], Ws[k * C + c], acc);
    if (BIAS_RELU) acc = fmaxf(acc + b[c], 0.0f);
    y[gid] = acc;
    if (DUAL16) y16[(long)node * 64 + c] = __float2half(acc);
}

// ---------------- gather at C=40: wave/node, lane=channel, padded fp16 rows ----------------
// out = dinv[d] * sum(w' * feat16[src]) + dinv[d]^2 * selfF[d] (+ b)
template <bool ADD_BIAS>
__global__ void gather40_k(const int* __restrict__ rowptr, const uint2* __restrict__ csr,
                           const __half* __restrict__ feat16, const float* __restrict__ selfF,
                           const float* __restrict__ dinv, const float* __restrict__ b,
                           float* __restrict__ out, int n) {
    int node = (int)(((long)blockIdx.x * blockDim.x + threadIdx.x) >> 6);
    int lane = threadIdx.x & 63;
    if (node >= n) return;
    int beg = __builtin_amdgcn_readfirstlane(rowptr[node]);
    int end = __builtin_amdgcn_readfirstlane(rowptr[node + 1]);
    if (lane >= 40) return;
    float accE = 0.0f;
    int t = beg;
    for (; t + 3 < end; t += 4) {
        uint2 q0 = csr[t], q1 = csr[t + 1], q2 = csr[t + 2], q3 = csr[t + 3];
        float v0 = __half2float(feat16[(long)q0.x * 64 + lane]);
        float v1 = __half2float(feat16[(long)q1.x * 64 + lane]);
        float v2 = __half2float(feat16[(long)q2.x * 64 + lane]);
        float v3 = __half2float(feat16[(long)q3.x * 64 + lane]);
        accE = fmaf(__uint_as_float(q0.y), v0, accE);
        accE = fmaf(__uint_as_float(q1.y), v1, accE);
        accE = fmaf(__uint_as_float(q2.y), v2, accE);
        accE = fmaf(__uint_as_float(q3.y), v3, accE);
    }
    for (; t < end; ++t) {
        uint2 q = csr[t];
        accE = fmaf(__uint_as_float(q.y), __half2float(feat16[(long)q.x * 64 + lane]), accE);
    }
    float di = dinv[node];
    float r = di * accE + di * di * selfF[(long)node * 40 + lane];
    if (ADD_BIAS) r += b[lane];
    out[(long)node * 40 + lane] = r;
}

extern "C" void kernel_launch(void* const* d_in, const int* in_sizes, int n_in,
                              void* d_out, int out_size, void* d_ws, size_t ws_size,
                              hipStream_t stream) {
    const float* x = (const float*)d_in[0];
    const int* ei = (const int*)d_in[1];
    const float* ew = (const float*)d_in[2];
    const float* W1 = (const float*)d_in[3];
    const float* b1 = (const float*)d_in[4];
    const float* W2 = (const float*)d_in[5];
    const float* b2 = (const float*)d_in[6];
    float* out = (float*)d_out;

    const int n = in_sizes[0] / 40;   // 100000
    const int e = in_sizes[2];        // 1600000
    const int* srcp = ei;
    const int* dstp = ei + e;
    const int NCB = (n + CNODES - 1) >> CSH;  // coarse buckets (98)
    const int M = NCB * 8;                    // streams

    // ws layout (4B units):
    // csr[2e] | tmp[2e] | dinv[n] | cnt[n] | rowptr[n+1] | bsum[64] |
    // cbcur[(M+1)*16] | cbase[(M+1)*16] | agg1/xl2_32[n*40] | h[n*64]
    // overlays: degcnt8 (16n words) at h (dead before linear1 writes h);
    //           sh16 (32n words = 2e when n=100k,e=1.6M) at tmp (dead after part2)
    uint2* csr = (uint2*)d_ws;
    ull* tmp = (ull*)(((int*)d_ws) + 2 * (long)e);
    float* dinv = (float*)(tmp + e);
    int* cnt = (int*)(dinv + n);
    int* rowptr = cnt + n;
    int* bsum = rowptr + n + 1;
    int* cbcur = bsum + 64;
    int* cbase = cbcur + (M + 1) * 16;
    float* agg1 = (float*)(cbase + (M + 1) * 16);
    float* h = agg1 + (long)n * 40;
    float* xl2_32 = agg1;                 // overlay: agg1 dead after linear1
    ull* degcnt8 = (ull*)(((uintptr_t)h + 7) & ~(uintptr_t)7);
    __half* sh16 = (__half*)tmp;          // overlay: tmp dead after part2

    const int B = 256;
    auto cdiv = [](long a, long b) { return (int)((a + b - 1) / b); };
    const int nb = cdiv(n, 2048);
    const int egrid = cdiv(e, EB);  // shared by count_deg_k / part1_k (class match!)

    // ---- degree, rowptr, coarse-stream cursors ----
    zero_k<<<cdiv((long)n * 8, B), B, 0, stream>>>(degcnt8, (long)n * 8);
    count_deg_k<<<egrid, B, 0, stream>>>(dstp, ew, degcnt8, n, e);
    dinv_k<<<cdiv(n, B), B, 0, stream>>>(degcnt8, dinv, cnt, n);
    scan1_k<<<nb, 256, 0, stream>>>(cnt, rowptr, bsum, n);
    scan2_k<<<1, 64, 0, stream>>>(bsum, nb, rowptr + n, e);
    scan3_k<<<cdiv(n, B), B, 0, stream>>>(rowptr, bsum, n);
    cbsum_k<<<NCB, 256, 0, stream>>>(degcnt8, cbcur + (M + 1) * 16 - 16 /*scratch end*/, n);
    // NOTE: cbsum written into tail scratch would alias; use dedicated cnt? -> use bsum-free area:
    // (use cnt as scratch is unsafe: cnt dead after scan1 -> safe!)
    cbsum_k<<<NCB, 256, 0, stream>>>(degcnt8, cnt, n);
    scancb_k<<<1, 256, 0, stream>>>(cnt, cbcur, cbase, M, e);
    part1_k<<<egrid, B, 0, stream>>>(srcp, dstp, ew, dinv, cbcur, tmp, e);
    part2_k<<<NCB, 1024, 0, stream>>>(tmp, cbase, rowptr, csr, n);

    // ---- x -> fp16 padded rows (edge operand for layer 1) ----
    tohalf_k<<<cdiv((long)n * 5, B), B, 0, stream>>>(x, sh16, n);

    // ---- layer 1: agg1 = A_norm @ x, h = relu(agg1 @ W1 + b1) ----
    gather40_k<false><<<cdiv((long)n * 64, B), B, 0, stream>>>(rowptr, csr, sh16, x, dinv, nullptr, agg1, n);
    linear_k<40, 64, true, false><<<cdiv((long)n * 64, B), B, 0, stream>>>(agg1, W1, b1, h, nullptr, n);

    // ---- layer 2: xl2 = h @ W2 (f32 + fp16 padded), out = A_norm @ xl2 + b2 ----
    linear_k<64, 40, false, true><<<cdiv((long)n * 40, B), B, 0, stream>>>(h, W2, nullptr, xl2_32, sh16, n);
    gather40_k<true><<<cdiv((long)n * 64, B), B, 0, stream>>>(rowptr, csr, sh16, xl2_32, dinv, b2, out, n);
}

// Round 10
// 368.263 us; speedup vs baseline: 3.1304x; 1.2264x over previous
//
#include <hip/hip_runtime.h>
#include <hip/hip_fp16.h>

// fixed-point scale for weighted-degree accumulation (2^25)
#define FIX 33554432.0f
#define FIXINV (1.0f / 33554432.0f)

typedef unsigned long long ull;

#define EB 1024     // edges per block in bcount/part1
#define CSH 9       // bucket = 512 dst nodes
#define CNODES 512
#define MAXNB 256   // static LDS histogram capacity (NB=196 here)

// ---------------- tiny zero ----------------
__global__ void zero_small_k(int* p, int total) {
    int i = blockIdx.x * blockDim.x + threadIdx.x;
    if (i < total) p[i] = 0;
}

// ---------------- bucket histogram: LDS hist -> 1 global atomic per (block,bucket) ----------------
__global__ void bcount_k(const int* __restrict__ dst, int* __restrict__ bcnt, int e, int NB) {
    __shared__ int lh[MAXNB];
    for (int i = threadIdx.x; i < NB; i += blockDim.x) lh[i] = 0;
    __syncthreads();
    int base = blockIdx.x * EB + threadIdx.x * 4;
    if (base + 3 < e) {
        int4 d4 = *reinterpret_cast<const int4*>(dst + base);
        atomicAdd(&lh[d4.x >> CSH], 1);
        atomicAdd(&lh[d4.y >> CSH], 1);
        atomicAdd(&lh[d4.z >> CSH], 1);
        atomicAdd(&lh[d4.w >> CSH], 1);
    } else {
        for (int i = base; i < e && i < base + 4; ++i) atomicAdd(&lh[dst[i] >> CSH], 1);
    }
    __syncthreads();
    for (int i = threadIdx.x; i < NB; i += blockDim.x) {
        int c = lh[i];
        if (c) atomicAdd(&bcnt[i * 16], c);
    }
}

// ---------------- exclusive scan of NB bucket counts (tiny, serial) ----------------
__global__ void bscan_k(const int* __restrict__ bcnt, int* __restrict__ bbase,
                        int* __restrict__ gcur, int NB, int e) {
    if (threadIdx.x == 0) {
        int run = 0;
        for (int i = 0; i < NB; ++i) {
            bbase[i] = run;
            gcur[i * 16] = run;
            run += bcnt[i * 16];
        }
        bbase[NB] = e;
    }
}

// ---------------- phase 1: LDS-staged bucket partition ----------------
// rec = ewbits[57:26] | src[25:9] | (dst&511)[8:0]
__global__ void part1_k(const int* __restrict__ src, const int* __restrict__ dst,
                        const float* __restrict__ ew, int* gcur, ull* __restrict__ tmp,
                        int e, int NB) {
    __shared__ int lh[MAXNB];
    __shared__ int lb[MAXNB];
    for (int i = threadIdx.x; i < NB; i += blockDim.x) lh[i] = 0;
    __syncthreads();
    int base = blockIdx.x * EB + threadIdx.x * 4;
    bool full = (blockIdx.x + 1) * EB <= e;  // block-uniform
    int bk[4], ls[4];
    ull rec[4];
    bool val[4];
    if (full) {
        int4 s4 = *reinterpret_cast<const int4*>(src + base);
        int4 d4 = *reinterpret_cast<const int4*>(dst + base);
        float4 e4 = *reinterpret_cast<const float4*>(ew + base);
        int s[4] = {s4.x, s4.y, s4.z, s4.w};
        int d[4] = {d4.x, d4.y, d4.z, d4.w};
        float ev[4] = {e4.x, e4.y, e4.z, e4.w};
#pragma unroll
        for (int j = 0; j < 4; ++j) {
            val[j] = true;
            bk[j] = d[j] >> CSH;
            rec[j] = ((ull)__float_as_uint(ev[j]) << 26) | ((ull)(unsigned)s[j] << 9) |
                     (ull)(unsigned)(d[j] & (CNODES - 1));
            ls[j] = atomicAdd(&lh[bk[j]], 1);
        }
    } else {
#pragma unroll
        for (int j = 0; j < 4; ++j) {
            int i = base + j;
            val[j] = (i < e);
            int s = val[j] ? src[i] : 0;
            int d = val[j] ? dst[i] : 0;
            float ev = val[j] ? ew[i] : 0.0f;
            bk[j] = d >> CSH;
            rec[j] = ((ull)__float_as_uint(ev) << 26) | ((ull)(unsigned)s << 9) |
                     (ull)(unsigned)(d & (CNODES - 1));
            ls[j] = val[j] ? atomicAdd(&lh[bk[j]], 1) : 0;
        }
    }
    __syncthreads();
    for (int i = threadIdx.x; i < NB; i += blockDim.x) {
        int c = lh[i];
        lb[i] = c ? atomicAdd(&gcur[i * 16], c) : 0;
    }
    __syncthreads();
#pragma unroll
    for (int j = 0; j < 4; ++j)
        if (val[j]) tmp[lb[bk[j]] + ls[j]] = rec[j];
}

// ---------------- phase 2: per-bucket cnt/deg/dinv/rowptr + node-sorted CSR ----------------
__global__ __launch_bounds__(CNODES) void part2_k(const ull* __restrict__ tmp,
                                                  const int* __restrict__ bbase,
                                                  float* __restrict__ dinv,
                                                  int* __restrict__ rowptr,
                                                  uint2* __restrict__ csr,
                                                  int n, int e, int NB) {
    __shared__ ull ldc[CNODES];   // hi32: cnt, lo32: fixed-point deg
    __shared__ int sc[CNODES];    // scan buffer, then global cursor
    int b = blockIdx.x;
    int tid = threadIdx.x;
    ldc[tid] = 0;
    __syncthreads();
    int beg = bbase[b], end = bbase[b + 1];
    // pass A: count + weighted degree (deterministic fixed-point)
    for (int i = beg + tid; i < end; i += CNODES) {
        ull rec = tmp[i];
        int dlo = (int)(rec & (CNODES - 1));
        float ewv = __uint_as_float((unsigned)(rec >> 26));
        atomicAdd(&ldc[dlo], (1ULL << 32) | (ull)__float2uint_rn(ewv * FIX));
    }
    __syncthreads();
    ull v = ldc[tid];
    int cnt = (int)(v >> 32);
    int node = b * CNODES + tid;
    if (node < n) {
        float d = (float)(unsigned)((unsigned)(v & 0xffffffffu) + (1u << 25)) * FIXINV;
        dinv[node] = rsqrtf(d);  // d >= 1 always
    }
    // inclusive scan of cnt over CNODES threads (Hillis-Steele)
    sc[tid] = cnt;
    __syncthreads();
    for (int off = 1; off < CNODES; off <<= 1) {
        int x = (tid >= off) ? sc[tid - off] : 0;
        __syncthreads();
        sc[tid] += x;
        __syncthreads();
    }
    int slotbase = beg + sc[tid] - cnt;  // global CSR base for this node
    if (node < n) rowptr[node] = slotbase;
    if (b == NB - 1 && tid == 0) rowptr[n] = e;
    __syncthreads();
    sc[tid] = slotbase;  // reuse as cursor
    __syncthreads();
    // pass B: scatter into node-sorted CSR (records L2-resident from pass A)
    for (int i = beg + tid; i < end; i += CNODES) {
        ull rec = tmp[i];
        int dlo = (int)(rec & (CNODES - 1));
        unsigned s = (unsigned)((rec >> 9) & 0x1FFFF);
        unsigned ewb = (unsigned)(rec >> 26);
        int slot = atomicAdd(&sc[dlo], 1);
        csr[slot] = make_uint2(s, ewb);
    }
}

// ---------------- x -> fp16 rows padded to 64 halves, pre-scaled by dinv ----------------
__global__ void tohalf_k(const float* __restrict__ x, const float* __restrict__ dinv,
                         __half* __restrict__ out, int n) {
    long gid = (long)blockIdx.x * blockDim.x + threadIdx.x;
    if (gid >= (long)n * 5) return;
    int row = (int)(gid / 5), c = (int)(gid % 5);
    float di = dinv[row];
    const float4* src = reinterpret_cast<const float4*>(x + (long)row * 40 + c * 8);
    float4 a = src[0], bb = src[1];
    __half2* dst = reinterpret_cast<__half2*>(out + (long)row * 64 + c * 8);
    dst[0] = __floats2half2_rn(di * a.x, di * a.y);
    dst[1] = __floats2half2_rn(di * a.z, di * a.w);
    dst[2] = __floats2half2_rn(di * bb.x, di * bb.y);
    dst[3] = __floats2half2_rn(di * bb.z, di * bb.w);
}

// ---------------- dense linear: y[n,C] = x[n,K] @ W[K,C] ----------------
// DUAL16 also emits fp16 copy scaled by dinv at row stride 64
template <int K, int C, bool BIAS_RELU, bool DUAL16>
__global__ void linear_k(const float* __restrict__ x, const float* __restrict__ W,
                         const float* __restrict__ b, float* __restrict__ y,
                         __half* __restrict__ y16, const float* __restrict__ dinv, int n) {
    __shared__ float Ws[K * C];
    for (int i = threadIdx.x; i < K * C; i += blockDim.x) Ws[i] = W[i];
    __syncthreads();
    long gid = (long)blockIdx.x * blockDim.x + threadIdx.x;
    int node = (int)(gid / C);
    int c = (int)(gid % C);
    if (node >= n) return;
    const float* xr = x + (long)node * K;
    float acc = 0.0f;
#pragma unroll
    for (int k = 0; k < K; ++k) acc = fmaf(xr[k], Ws[k * C + c], acc);
    if (BIAS_RELU) acc = fmaxf(acc + b[c], 0.0f);
    y[gid] = acc;
    if (DUAL16) y16[(long)node * 64 + c] = __float2half(dinv[node] * acc);
}

// ---------------- gather at C=40: wave/node, lane=channel, dinv-folded fp16 rows ----------------
// out = dinv[d] * sum(ew * feat16'[src]) + dinv[d]^2 * selfF[d] (+ b);  feat16' = dinv*feat
template <bool ADD_BIAS>
__global__ void gather40_k(const int* __restrict__ rowptr, const uint2* __restrict__ csr,
                           const __half* __restrict__ feat16, const float* __restrict__ selfF,
                           const float* __restrict__ dinv, const float* __restrict__ b,
                           float* __restrict__ out, int n) {
    int node = (int)(((long)blockIdx.x * blockDim.x + threadIdx.x) >> 6);
    int lane = threadIdx.x & 63;
    if (node >= n) return;
    int beg = __builtin_amdgcn_readfirstlane(rowptr[node]);
    int end = __builtin_amdgcn_readfirstlane(rowptr[node + 1]);
    if (lane >= 40) return;
    float accE = 0.0f;
    int t = beg;
    for (; t + 3 < end; t += 4) {
        uint2 q0 = csr[t], q1 = csr[t + 1], q2 = csr[t + 2], q3 = csr[t + 3];
        float v0 = __half2float(feat16[(long)q0.x * 64 + lane]);
        float v1 = __half2float(feat16[(long)q1.x * 64 + lane]);
        float v2 = __half2float(feat16[(long)q2.x * 64 + lane]);
        float v3 = __half2float(feat16[(long)q3.x * 64 + lane]);
        accE = fmaf(__uint_as_float(q0.y), v0, accE);
        accE = fmaf(__uint_as_float(q1.y), v1, accE);
        accE = fmaf(__uint_as_float(q2.y), v2, accE);
        accE = fmaf(__uint_as_float(q3.y), v3, accE);
    }
    for (; t < end; ++t) {
        uint2 q = csr[t];
        accE = fmaf(__uint_as_float(q.y), __half2float(feat16[(long)q.x * 64 + lane]), accE);
    }
    float di = dinv[node];
    float r = di * accE + di * di * selfF[(long)node * 40 + lane];
    if (ADD_BIAS) r += b[lane];
    out[(long)node * 40 + lane] = r;
}

extern "C" void kernel_launch(void* const* d_in, const int* in_sizes, int n_in,
                              void* d_out, int out_size, void* d_ws, size_t ws_size,
                              hipStream_t stream) {
    const float* x = (const float*)d_in[0];
    const int* ei = (const int*)d_in[1];
    const float* ew = (const float*)d_in[2];
    const float* W1 = (const float*)d_in[3];
    const float* b1 = (const float*)d_in[4];
    const float* W2 = (const float*)d_in[5];
    const float* b2 = (const float*)d_in[6];
    float* out = (float*)d_out;

    const int n = in_sizes[0] / 40;   // 100000
    const int e = in_sizes[2];        // 1600000
    const int* srcp = ei;
    const int* dstp = ei + e;
    const int NB = (n + CNODES - 1) >> CSH;  // 196 buckets

    // ws layout (4B units):
    // csr[2e] | tmp[2e] | dinv[n] | rowptr[n+1] | bbase[NB+1] | bcnt[NB*16] | gcur[NB*16] |
    // agg1/xl2_32[n*40] | h[n*64]
    // sh16 (64n halves = 32n words = 2e words at n=100k) overlays tmp (dead after part2)
    uint2* csr = (uint2*)d_ws;
    ull* tmp = (ull*)(((int*)d_ws) + 2 * (long)e);
    float* dinv = (float*)(tmp + e);
    int* rowptr = (int*)(dinv + n);
    int* bbase = rowptr + n + 1;
    int* bcnt = bbase + NB + 1;
    int* gcur = bcnt + NB * 16;
    float* agg1 = (float*)(gcur + NB * 16);
    float* h = agg1 + (long)n * 40;
    float* xl2_32 = agg1;                 // overlay: agg1 dead after linear1
    __half* sh16 = (__half*)tmp;          // overlay: tmp dead after part2

    const int B = 256;
    auto cdiv = [](long a, long b) { return (int)((a + b - 1) / b); };
    const int egrid = cdiv(e, EB);

    // ---- CSR build (shared by both layers) ----
    zero_small_k<<<cdiv(NB * 16, B), B, 0, stream>>>(bcnt, NB * 16);
    bcount_k<<<egrid, B, 0, stream>>>(dstp, bcnt, e, NB);
    bscan_k<<<1, 64, 0, stream>>>(bcnt, bbase, gcur, NB, e);
    part1_k<<<egrid, B, 0, stream>>>(srcp, dstp, ew, gcur, tmp, e, NB);
    part2_k<<<NB, CNODES, 0, stream>>>(tmp, bbase, dinv, rowptr, csr, n, e, NB);

    // ---- x -> fp16 (dinv-folded, padded rows) ----
    tohalf_k<<<cdiv((long)n * 5, B), B, 0, stream>>>(x, dinv, sh16, n);

    // ---- layer 1: agg1 = A_norm @ x, h = relu(agg1 @ W1 + b1) ----
    gather40_k<false><<<cdiv((long)n * 64, B), B, 0, stream>>>(rowptr, csr, sh16, x, dinv, nullptr, agg1, n);
    linear_k<40, 64, true, false><<<cdiv((long)n * 64, B), B, 0, stream>>>(agg1, W1, b1, h, nullptr, nullptr, n);

    // ---- layer 2: xl2 = h @ W2 (f32 + dinv-folded fp16), out = A_norm @ xl2 + b2 ----
    linear_k<64, 40, false, true><<<cdiv((long)n * 40, B), B, 0, stream>>>(h, W2, nullptr, xl2_32, sh16, dinv, n);
    gather40_k<true><<<cdiv((long)n * 64, B), B, 0, stream>>>(rowptr, csr, sh16, xl2_32, dinv, b2, out, n);
}

// Round 11
// 328.640 us; speedup vs baseline: 3.5079x; 1.1206x over previous
//
#include <hip/hip_runtime.h>
#include <hip/hip_fp16.h>

// fixed-point scale for weighted-degree accumulation (2^25)
#define FIX 33554432.0f
#define FIXINV (1.0f / 33554432.0f)

typedef unsigned long long ull;

#define EB 1024     // edges per block in bcount/part1
#define CSH 9       // bucket = 512 dst nodes
#define CNODES 512
#define MAXNB 256   // static LDS histogram capacity (NB=196 here)

// ---------------- tiny zero ----------------
__global__ void zero_small_k(int* p, int total) {
    int i = blockIdx.x * blockDim.x + threadIdx.x;
    if (i < total) p[i] = 0;
}

// ---------------- bucket histogram: LDS hist -> 1 global atomic per (block,bucket) ----------------
__global__ void bcount_k(const int* __restrict__ dst, int* __restrict__ bcnt, int e, int NB) {
    __shared__ int lh[MAXNB];
    for (int i = threadIdx.x; i < NB; i += blockDim.x) lh[i] = 0;
    __syncthreads();
    int base = blockIdx.x * EB + threadIdx.x * 4;
    if (base + 3 < e) {
        int4 d4 = *reinterpret_cast<const int4*>(dst + base);
        atomicAdd(&lh[d4.x >> CSH], 1);
        atomicAdd(&lh[d4.y >> CSH], 1);
        atomicAdd(&lh[d4.z >> CSH], 1);
        atomicAdd(&lh[d4.w >> CSH], 1);
    } else {
        for (int i = base; i < e && i < base + 4; ++i) atomicAdd(&lh[dst[i] >> CSH], 1);
    }
    __syncthreads();
    for (int i = threadIdx.x; i < NB; i += blockDim.x) {
        int c = lh[i];
        if (c) atomicAdd(&bcnt[i * 16], c);
    }
}

// ---------------- exclusive scan of NB bucket counts (tiny, serial) ----------------
__global__ void bscan_k(const int* __restrict__ bcnt, int* __restrict__ bbase,
                        int* __restrict__ gcur, int NB, int e) {
    if (threadIdx.x == 0) {
        int run = 0;
        for (int i = 0; i < NB; ++i) {
            bbase[i] = run;
            gcur[i * 16] = run;
            run += bcnt[i * 16];
        }
        bbase[NB] = e;
    }
}

// ---------------- phase 1: LDS-staged bucket partition ----------------
// rec = ewbits[57:26] | src[25:9] | (dst&511)[8:0]
__global__ void part1_k(const int* __restrict__ src, const int* __restrict__ dst,
                        const float* __restrict__ ew, int* gcur, ull* __restrict__ tmp,
                        int e, int NB) {
    __shared__ int lh[MAXNB];
    __shared__ int lb[MAXNB];
    for (int i = threadIdx.x; i < NB; i += blockDim.x) lh[i] = 0;
    __syncthreads();
    int base = blockIdx.x * EB + threadIdx.x * 4;
    bool full = (blockIdx.x + 1) * EB <= e;  // block-uniform
    int bk[4], ls[4];
    ull rec[4];
    bool val[4];
    if (full) {
        int4 s4 = *reinterpret_cast<const int4*>(src + base);
        int4 d4 = *reinterpret_cast<const int4*>(dst + base);
        float4 e4 = *reinterpret_cast<const float4*>(ew + base);
        int s[4] = {s4.x, s4.y, s4.z, s4.w};
        int d[4] = {d4.x, d4.y, d4.z, d4.w};
        float ev[4] = {e4.x, e4.y, e4.z, e4.w};
#pragma unroll
        for (int j = 0; j < 4; ++j) {
            val[j] = true;
            bk[j] = d[j] >> CSH;
            rec[j] = ((ull)__float_as_uint(ev[j]) << 26) | ((ull)(unsigned)s[j] << 9) |
                     (ull)(unsigned)(d[j] & (CNODES - 1));
            ls[j] = atomicAdd(&lh[bk[j]], 1);
        }
    } else {
#pragma unroll
        for (int j = 0; j < 4; ++j) {
            int i = base + j;
            val[j] = (i < e);
            int s = val[j] ? src[i] : 0;
            int d = val[j] ? dst[i] : 0;
            float ev = val[j] ? ew[i] : 0.0f;
            bk[j] = d >> CSH;
            rec[j] = ((ull)__float_as_uint(ev) << 26) | ((ull)(unsigned)s << 9) |
                     (ull)(unsigned)(d & (CNODES - 1));
            ls[j] = val[j] ? atomicAdd(&lh[bk[j]], 1) : 0;
        }
    }
    __syncthreads();
    for (int i = threadIdx.x; i < NB; i += blockDim.x) {
        int c = lh[i];
        lb[i] = c ? atomicAdd(&gcur[i * 16], c) : 0;
    }
    __syncthreads();
#pragma unroll
    for (int j = 0; j < 4; ++j)
        if (val[j]) tmp[lb[bk[j]] + ls[j]] = rec[j];
}

// ---------------- phase 2: per-bucket cnt/deg/dinv/rowptr + node-sorted CSR ----------------
__global__ __launch_bounds__(CNODES) void part2_k(const ull* __restrict__ tmp,
                                                  const int* __restrict__ bbase,
                                                  float* __restrict__ dinv,
                                                  int* __restrict__ rowptr,
                                                  uint2* __restrict__ csr,
                                                  int n, int e, int NB) {
    __shared__ ull ldc[CNODES];   // hi32: cnt, lo32: fixed-point deg
    __shared__ int sc[CNODES];    // scan buffer, then global cursor
    int b = blockIdx.x;
    int tid = threadIdx.x;
    ldc[tid] = 0;
    __syncthreads();
    int beg = bbase[b], end = bbase[b + 1];
    // pass A: count + weighted degree (deterministic fixed-point)
    for (int i = beg + tid; i < end; i += CNODES) {
        ull rec = tmp[i];
        int dlo = (int)(rec & (CNODES - 1));
        float ewv = __uint_as_float((unsigned)(rec >> 26));
        atomicAdd(&ldc[dlo], (1ULL << 32) | (ull)__float2uint_rn(ewv * FIX));
    }
    __syncthreads();
    ull v = ldc[tid];
    int cnt = (int)(v >> 32);
    int node = b * CNODES + tid;
    if (node < n) {
        float d = (float)(unsigned)((unsigned)(v & 0xffffffffu) + (1u << 25)) * FIXINV;
        dinv[node] = rsqrtf(d);  // d >= 1 always
    }
    // inclusive scan of cnt over CNODES threads (Hillis-Steele)
    sc[tid] = cnt;
    __syncthreads();
    for (int off = 1; off < CNODES; off <<= 1) {
        int x = (tid >= off) ? sc[tid - off] : 0;
        __syncthreads();
        sc[tid] += x;
        __syncthreads();
    }
    int slotbase = beg + sc[tid] - cnt;  // global CSR base for this node
    if (node < n) rowptr[node] = slotbase;
    if (b == NB - 1 && tid == 0) rowptr[n] = e;
    __syncthreads();
    sc[tid] = slotbase;  // reuse as cursor
    __syncthreads();
    // pass B: scatter into node-sorted CSR (records L2-resident from pass A)
    for (int i = beg + tid; i < end; i += CNODES) {
        ull rec = tmp[i];
        int dlo = (int)(rec & (CNODES - 1));
        unsigned s = (unsigned)((rec >> 9) & 0x1FFFF);
        unsigned ewb = (unsigned)(rec >> 26);
        int slot = atomicAdd(&sc[dlo], 1);
        csr[slot] = make_uint2(s, ewb);
    }
}

// ---------------- x -> fp16 rows padded to 64 halves, pre-scaled by dinv ----------------
__global__ void tohalf_k(const float* __restrict__ x, const float* __restrict__ dinv,
                         __half* __restrict__ out, int n) {
    long gid = (long)blockIdx.x * blockDim.x + threadIdx.x;
    if (gid >= (long)n * 5) return;
    int row = (int)(gid / 5), c = (int)(gid % 5);
    float di = dinv[row];
    const float4* src = reinterpret_cast<const float4*>(x + (long)row * 40 + c * 8);
    float4 a = src[0], bb = src[1];
    __half2* dst = reinterpret_cast<__half2*>(out + (long)row * 64 + c * 8);
    dst[0] = __floats2half2_rn(di * a.x, di * a.y);
    dst[1] = __floats2half2_rn(di * a.z, di * a.w);
    dst[2] = __floats2half2_rn(di * bb.x, di * bb.y);
    dst[3] = __floats2half2_rn(di * bb.z, di * bb.w);
}

// ---------------- dense linear, wave-per-node: W columns in VGPRs, x row via SMEM ----------------
// y[n,C] = x[n,K] @ W[K,C]; BIAS_RELU: relu(y+b); DUAL16: also emit fp16 dinv-scaled copy
template <int K, int C, bool BIAS_RELU, bool DUAL16>
__global__ void linear_k(const float* __restrict__ x, const float* __restrict__ W,
                         const float* __restrict__ b, float* __restrict__ y,
                         __half* __restrict__ y16, const float* __restrict__ dinv, int n) {
    int lane = threadIdx.x & 63;
    int wid = blockIdx.x * (blockDim.x >> 6) + (threadIdx.x >> 6);
    int nwaves = gridDim.x * (blockDim.x >> 6);
    float wreg[K];
    float bias = 0.0f;
#pragma unroll
    for (int k = 0; k < K; ++k) wreg[k] = (lane < C) ? W[k * C + lane] : 0.0f;
    if (BIAS_RELU && lane < C) bias = b[lane];
    for (int node = wid; node < n; node += nwaves) {
        int un = __builtin_amdgcn_readfirstlane(node);  // force SGPR base -> s_load row
        const float* xr = x + (long)un * K;
        float acc = 0.0f;
#pragma unroll
        for (int k = 0; k < K; ++k) acc = fmaf(xr[k], wreg[k], acc);
        if (BIAS_RELU) acc = fmaxf(acc + bias, 0.0f);
        if (lane < C) {
            y[(long)un * C + lane] = acc;
            if (DUAL16) y16[(long)un * 64 + lane] = __float2half(dinv[un] * acc);
        }
    }
}

// ---------------- gather at C=40: wave/node, lane=channel, dinv-folded fp16 rows ----------------
// out = dinv[d] * sum(ew * feat16'[src]) + dinv[d]^2 * selfF[d] (+ b);  feat16' = dinv*feat
template <bool ADD_BIAS>
__global__ void gather40_k(const int* __restrict__ rowptr, const uint2* __restrict__ csr,
                           const __half* __restrict__ feat16, const float* __restrict__ selfF,
                           const float* __restrict__ dinv, const float* __restrict__ b,
                           float* __restrict__ out, int n) {
    int node = (int)(((long)blockIdx.x * blockDim.x + threadIdx.x) >> 6);
    int lane = threadIdx.x & 63;
    if (node >= n) return;
    int beg = __builtin_amdgcn_readfirstlane(rowptr[node]);
    int end = __builtin_amdgcn_readfirstlane(rowptr[node + 1]);
    if (lane >= 40) return;
    float accE = 0.0f;
    int t = beg;
    for (; t + 3 < end; t += 4) {
        uint2 q0 = csr[t], q1 = csr[t + 1], q2 = csr[t + 2], q3 = csr[t + 3];
        float v0 = __half2float(feat16[(long)q0.x * 64 + lane]);
        float v1 = __half2float(feat16[(long)q1.x * 64 + lane]);
        float v2 = __half2float(feat16[(long)q2.x * 64 + lane]);
        float v3 = __half2float(feat16[(long)q3.x * 64 + lane]);
        accE = fmaf(__uint_as_float(q0.y), v0, accE);
        accE = fmaf(__uint_as_float(q1.y), v1, accE);
        accE = fmaf(__uint_as_float(q2.y), v2, accE);
        accE = fmaf(__uint_as_float(q3.y), v3, accE);
    }
    for (; t < end; ++t) {
        uint2 q = csr[t];
        accE = fmaf(__uint_as_float(q.y), __half2float(feat16[(long)q.x * 64 + lane]), accE);
    }
    float di = dinv[node];
    float r = di * accE + di * di * selfF[(long)node * 40 + lane];
    if (ADD_BIAS) r += b[lane];
    out[(long)node * 40 + lane] = r;
}

extern "C" void kernel_launch(void* const* d_in, const int* in_sizes, int n_in,
                              void* d_out, int out_size, void* d_ws, size_t ws_size,
                              hipStream_t stream) {
    const float* x = (const float*)d_in[0];
    const int* ei = (const int*)d_in[1];
    const float* ew = (const float*)d_in[2];
    const float* W1 = (const float*)d_in[3];
    const float* b1 = (const float*)d_in[4];
    const float* W2 = (const float*)d_in[5];
    const float* b2 = (const float*)d_in[6];
    float* out = (float*)d_out;

    const int n = in_sizes[0] / 40;   // 100000
    const int e = in_sizes[2];        // 1600000
    const int* srcp = ei;
    const int* dstp = ei + e;
    const int NB = (n + CNODES - 1) >> CSH;  // 196 buckets

    // ws layout (4B units):
    // csr[2e] | tmp[2e] | dinv[n] | rowptr[n+1] | bbase[NB+1] | bcnt[NB*16] | gcur[NB*16] |
    // agg1/xl2_32[n*40] | h[n*64]
    // sh16 (64n halves = 32n words = 2e words at n=100k) overlays tmp (dead after part2)
    uint2* csr = (uint2*)d_ws;
    ull* tmp = (ull*)(((int*)d_ws) + 2 * (long)e);
    float* dinv = (float*)(tmp + e);
    int* rowptr = (int*)(dinv + n);
    int* bbase = rowptr + n + 1;
    int* bcnt = bbase + NB + 1;
    int* gcur = bcnt + NB * 16;
    float* agg1 = (float*)(gcur + NB * 16);
    float* h = agg1 + (long)n * 40;
    float* xl2_32 = agg1;                 // overlay: agg1 dead after linear1
    __half* sh16 = (__half*)tmp;          // overlay: tmp dead after part2

    const int B = 256;
    auto cdiv = [](long a, long b) { return (int)((a + b - 1) / b); };
    const int egrid = cdiv(e, EB);

    // ---- CSR build (shared by both layers) ----
    zero_small_k<<<cdiv(NB * 16, B), B, 0, stream>>>(bcnt, NB * 16);
    bcount_k<<<egrid, B, 0, stream>>>(dstp, bcnt, e, NB);
    bscan_k<<<1, 64, 0, stream>>>(bcnt, bbase, gcur, NB, e);
    part1_k<<<egrid, B, 0, stream>>>(srcp, dstp, ew, gcur, tmp, e, NB);
    part2_k<<<NB, CNODES, 0, stream>>>(tmp, bbase, dinv, rowptr, csr, n, e, NB);

    // ---- x -> fp16 (dinv-folded, padded rows) ----
    tohalf_k<<<cdiv((long)n * 5, B), B, 0, stream>>>(x, dinv, sh16, n);

    // ---- layer 1: agg1 = A_norm @ x, h = relu(agg1 @ W1 + b1) ----
    gather40_k<false><<<cdiv((long)n * 64, B), B, 0, stream>>>(rowptr, csr, sh16, x, dinv, nullptr, agg1, n);
    linear_k<40, 64, true, false><<<1024, B, 0, stream>>>(agg1, W1, b1, h, nullptr, nullptr, n);

    // ---- layer 2: xl2 = h @ W2 (f32 + dinv-folded fp16), out = A_norm @ xl2 + b2 ----
    linear_k<64, 40, false, true><<<1024, B, 0, stream>>>(h, W2, nullptr, xl2_32, sh16, dinv, n);
    gather40_k<true><<<cdiv((long)n * 64, B), B, 0, stream>>>(rowptr, csr, sh16, xl2_32, dinv, b2, out, n);
}

// Round 12
// 320.790 us; speedup vs baseline: 3.5937x; 1.0245x over previous
//
#include <hip/hip_runtime.h>
#include <hip/hip_fp16.h>

// fixed-point scale for weighted-degree accumulation (2^25)
#define FIX 33554432.0f
#define FIXINV (1.0f / 33554432.0f)

typedef unsigned long long ull;

#define EB 1024     // edges per block in bcount/part1
#define CSH 9       // bucket = 512 dst nodes
#define CNODES 512
#define MAXNB 256   // static LDS histogram capacity (NB=196 here)

// ---------------- tiny zero ----------------
__global__ void zero_small_k(int* p, int total) {
    int i = blockIdx.x * blockDim.x + threadIdx.x;
    if (i < total) p[i] = 0;
}

// ---------------- bucket histogram: LDS hist -> 1 global atomic per (block,bucket) ----------------
__global__ void bcount_k(const int* __restrict__ dst, int* __restrict__ bcnt, int e, int NB) {
    __shared__ int lh[MAXNB];
    for (int i = threadIdx.x; i < NB; i += blockDim.x) lh[i] = 0;
    __syncthreads();
    int base = blockIdx.x * EB + threadIdx.x * 4;
    if (base + 3 < e) {
        int4 d4 = *reinterpret_cast<const int4*>(dst + base);
        atomicAdd(&lh[d4.x >> CSH], 1);
        atomicAdd(&lh[d4.y >> CSH], 1);
        atomicAdd(&lh[d4.z >> CSH], 1);
        atomicAdd(&lh[d4.w >> CSH], 1);
    } else {
        for (int i = base; i < e && i < base + 4; ++i) atomicAdd(&lh[dst[i] >> CSH], 1);
    }
    __syncthreads();
    for (int i = threadIdx.x; i < NB; i += blockDim.x) {
        int c = lh[i];
        if (c) atomicAdd(&bcnt[i * 16], c);
    }
}

// ---------------- exclusive scan of NB bucket counts (tiny, serial) ----------------
__global__ void bscan_k(const int* __restrict__ bcnt, int* __restrict__ bbase,
                        int* __restrict__ gcur, int NB, int e) {
    if (threadIdx.x == 0) {
        int run = 0;
        for (int i = 0; i < NB; ++i) {
            bbase[i] = run;
            gcur[i * 16] = run;
            run += bcnt[i * 16];
        }
        bbase[NB] = e;
    }
}

// ---------------- phase 1: LDS-staged bucket partition ----------------
// rec = ewbits[57:26] | src[25:9] | (dst&511)[8:0]
__global__ void part1_k(const int* __restrict__ src, const int* __restrict__ dst,
                        const float* __restrict__ ew, int* gcur, ull* __restrict__ tmp,
                        int e, int NB) {
    __shared__ int lh[MAXNB];
    __shared__ int lb[MAXNB];
    for (int i = threadIdx.x; i < NB; i += blockDim.x) lh[i] = 0;
    __syncthreads();
    int base = blockIdx.x * EB + threadIdx.x * 4;
    bool full = (blockIdx.x + 1) * EB <= e;  // block-uniform
    int bk[4], ls[4];
    ull rec[4];
    bool val[4];
    if (full) {
        int4 s4 = *reinterpret_cast<const int4*>(src + base);
        int4 d4 = *reinterpret_cast<const int4*>(dst + base);
        float4 e4 = *reinterpret_cast<const float4*>(ew + base);
        int s[4] = {s4.x, s4.y, s4.z, s4.w};
        int d[4] = {d4.x, d4.y, d4.z, d4.w};
        float ev[4] = {e4.x, e4.y, e4.z, e4.w};
#pragma unroll
        for (int j = 0; j < 4; ++j) {
            val[j] = true;
            bk[j] = d[j] >> CSH;
            rec[j] = ((ull)__float_as_uint(ev[j]) << 26) | ((ull)(unsigned)s[j] << 9) |
                     (ull)(unsigned)(d[j] & (CNODES - 1));
            ls[j] = atomicAdd(&lh[bk[j]], 1);
        }
    } else {
#pragma unroll
        for (int j = 0; j < 4; ++j) {
            int i = base + j;
            val[j] = (i < e);
            int s = val[j] ? src[i] : 0;
            int d = val[j] ? dst[i] : 0;
            float ev = val[j] ? ew[i] : 0.0f;
            bk[j] = d >> CSH;
            rec[j] = ((ull)__float_as_uint(ev) << 26) | ((ull)(unsigned)s << 9) |
                     (ull)(unsigned)(d & (CNODES - 1));
            ls[j] = val[j] ? atomicAdd(&lh[bk[j]], 1) : 0;
        }
    }
    __syncthreads();
    for (int i = threadIdx.x; i < NB; i += blockDim.x) {
        int c = lh[i];
        lb[i] = c ? atomicAdd(&gcur[i * 16], c) : 0;
    }
    __syncthreads();
#pragma unroll
    for (int j = 0; j < 4; ++j)
        if (val[j]) tmp[lb[bk[j]] + ls[j]] = rec[j];
}

// ---------------- phase 2: per-bucket cnt/deg/dinv/rowptr + node-sorted CSR ----------------
__global__ __launch_bounds__(CNODES) void part2_k(const ull* __restrict__ tmp,
                                                  const int* __restrict__ bbase,
                                                  float* __restrict__ dinv,
                                                  int* __restrict__ rowptr,
                                                  uint2* __restrict__ csr,
                                                  int n, int e, int NB) {
    __shared__ ull ldc[CNODES];   // hi32: cnt, lo32: fixed-point deg
    __shared__ int sc[CNODES];    // scan buffer, then global cursor
    int b = blockIdx.x;
    int tid = threadIdx.x;
    ldc[tid] = 0;
    __syncthreads();
    int beg = bbase[b], end = bbase[b + 1];
    // pass A: count + weighted degree (deterministic fixed-point)
    for (int i = beg + tid; i < end; i += CNODES) {
        ull rec = tmp[i];
        int dlo = (int)(rec & (CNODES - 1));
        float ewv = __uint_as_float((unsigned)(rec >> 26));
        atomicAdd(&ldc[dlo], (1ULL << 32) | (ull)__float2uint_rn(ewv * FIX));
    }
    __syncthreads();
    ull v = ldc[tid];
    int cnt = (int)(v >> 32);
    int node = b * CNODES + tid;
    if (node < n) {
        float d = (float)(unsigned)((unsigned)(v & 0xffffffffu) + (1u << 25)) * FIXINV;
        dinv[node] = rsqrtf(d);  // d >= 1 always
    }
    // inclusive scan of cnt over CNODES threads (Hillis-Steele)
    sc[tid] = cnt;
    __syncthreads();
    for (int off = 1; off < CNODES; off <<= 1) {
        int x = (tid >= off) ? sc[tid - off] : 0;
        __syncthreads();
        sc[tid] += x;
        __syncthreads();
    }
    int slotbase = beg + sc[tid] - cnt;  // global CSR base for this node
    if (node < n) rowptr[node] = slotbase;
    if (b == NB - 1 && tid == 0) rowptr[n] = e;
    __syncthreads();
    sc[tid] = slotbase;  // reuse as cursor
    __syncthreads();
    // pass B: scatter into node-sorted CSR (records L2-resident from pass A)
    for (int i = beg + tid; i < end; i += CNODES) {
        ull rec = tmp[i];
        int dlo = (int)(rec & (CNODES - 1));
        unsigned s = (unsigned)((rec >> 9) & 0x1FFFF);
        unsigned ewb = (unsigned)(rec >> 26);
        int slot = atomicAdd(&sc[dlo], 1);
        csr[slot] = make_uint2(s, ewb);
    }
}

// ---------------- x -> fp16 rows padded to 64 halves, pre-scaled by dinv ----------------
__global__ void tohalf_k(const float* __restrict__ x, const float* __restrict__ dinv,
                         __half* __restrict__ out, int n) {
    long gid = (long)blockIdx.x * blockDim.x + threadIdx.x;
    if (gid >= (long)n * 5) return;
    int row = (int)(gid / 5), c = (int)(gid % 5);
    float di = dinv[row];
    const float4* src = reinterpret_cast<const float4*>(x + (long)row * 40 + c * 8);
    float4 a = src[0], bb = src[1];
    __half2* dst = reinterpret_cast<__half2*>(out + (long)row * 64 + c * 8);
    dst[0] = __floats2half2_rn(di * a.x, di * a.y);
    dst[1] = __floats2half2_rn(di * a.z, di * a.w);
    dst[2] = __floats2half2_rn(di * bb.x, di * bb.y);
    dst[3] = __floats2half2_rn(di * bb.z, di * bb.w);
}

// ---------------- dense linear, wave-per-node: W in VGPRs, x row via SMEM ----------------
// y[n,C] = x[n,K] @ W[K,C]; 4 independent accumulators break the FMA dependence chain
template <int K, int C, bool BIAS_RELU, bool DUAL16>
__global__ __launch_bounds__(256) void linear_k(const float* __restrict__ x,
                                                const float* __restrict__ W,
                                                const float* __restrict__ b,
                                                float* __restrict__ y,
                                                __half* __restrict__ y16,
                                                const float* __restrict__ dinv, int n) {
    int lane = threadIdx.x & 63;
    int wid = blockIdx.x * (blockDim.x >> 6) + (threadIdx.x >> 6);
    int nwaves = gridDim.x * (blockDim.x >> 6);
    float wreg[K];
#pragma unroll
    for (int k = 0; k < K; ++k) wreg[k] = (lane < C) ? W[k * C + lane] : 0.0f;
    float bias = (BIAS_RELU && lane < C) ? b[lane] : 0.0f;
    for (int node = wid; node < n; node += nwaves) {
        int un = __builtin_amdgcn_readfirstlane(node);  // force SGPR base -> s_load row
        const float* xr = x + (long)un * K;
        float a0 = 0.0f, a1 = 0.0f, a2 = 0.0f, a3 = 0.0f;
#pragma unroll
        for (int k = 0; k < K; k += 4) {
            a0 = fmaf(xr[k + 0], wreg[k + 0], a0);
            a1 = fmaf(xr[k + 1], wreg[k + 1], a1);
            a2 = fmaf(xr[k + 2], wreg[k + 2], a2);
            a3 = fmaf(xr[k + 3], wreg[k + 3], a3);
        }
        float acc = (a0 + a1) + (a2 + a3);
        if (BIAS_RELU) acc = fmaxf(acc + bias, 0.0f);
        if (lane < C) {
            y[(long)un * C + lane] = acc;
            if (DUAL16) y16[(long)un * 64 + lane] = __float2half(dinv[un] * acc);
        }
    }
}

// ---------------- gather at C=40: wave/node, lane=channel, dinv-folded fp16 rows ----------------
// out = dinv[d] * sum(ew * feat16'[src]) + dinv[d]^2 * selfF[d] (+ b);  feat16' = dinv*feat
template <bool ADD_BIAS>
__global__ void gather40_k(const int* __restrict__ rowptr, const uint2* __restrict__ csr,
                           const __half* __restrict__ feat16, const float* __restrict__ selfF,
                           const float* __restrict__ dinv, const float* __restrict__ b,
                           float* __restrict__ out, int n) {
    int node = (int)(((long)blockIdx.x * blockDim.x + threadIdx.x) >> 6);
    int lane = threadIdx.x & 63;
    if (node >= n) return;
    int beg = __builtin_amdgcn_readfirstlane(rowptr[node]);
    int end = __builtin_amdgcn_readfirstlane(rowptr[node + 1]);
    if (lane >= 40) return;
    float accE = 0.0f;
    int t = beg;
    for (; t + 3 < end; t += 4) {
        uint2 q0 = csr[t], q1 = csr[t + 1], q2 = csr[t + 2], q3 = csr[t + 3];
        float v0 = __half2float(feat16[(long)q0.x * 64 + lane]);
        float v1 = __half2float(feat16[(long)q1.x * 64 + lane]);
        float v2 = __half2float(feat16[(long)q2.x * 64 + lane]);
        float v3 = __half2float(feat16[(long)q3.x * 64 + lane]);
        accE = fmaf(__uint_as_float(q0.y), v0, accE);
        accE = fmaf(__uint_as_float(q1.y), v1, accE);
        accE = fmaf(__uint_as_float(q2.y), v2, accE);
        accE = fmaf(__uint_as_float(q3.y), v3, accE);
    }
    for (; t < end; ++t) {
        uint2 q = csr[t];
        accE = fmaf(__uint_as_float(q.y), __half2float(feat16[(long)q.x * 64 + lane]), accE);
    }
    float di = dinv[node];
    float r = di * accE + di * di * selfF[(long)node * 40 + lane];
    if (ADD_BIAS) r += b[lane];
    out[(long)node * 40 + lane] = r;
}

extern "C" void kernel_launch(void* const* d_in, const int* in_sizes, int n_in,
                              void* d_out, int out_size, void* d_ws, size_t ws_size,
                              hipStream_t stream) {
    const float* x = (const float*)d_in[0];
    const int* ei = (const int*)d_in[1];
    const float* ew = (const float*)d_in[2];
    const float* W1 = (const float*)d_in[3];
    const float* b1 = (const float*)d_in[4];
    const float* W2 = (const float*)d_in[5];
    const float* b2 = (const float*)d_in[6];
    float* out = (float*)d_out;

    const int n = in_sizes[0] / 40;   // 100000
    const int e = in_sizes[2];        // 1600000
    const int* srcp = ei;
    const int* dstp = ei + e;
    const int NB = (n + CNODES - 1) >> CSH;  // 196 buckets

    // ws layout (4B units):
    // csr[2e] | tmp[2e] | dinv[n] | rowptr[n+1] | bbase[NB+1] | bcnt[NB*16] | gcur[NB*16] |
    // agg1/xl2_32[n*40] | h[n*64]
    // sh16 (64n halves = 32n words = 2e words at n=100k) overlays tmp (dead after part2)
    uint2* csr = (uint2*)d_ws;
    ull* tmp = (ull*)(((int*)d_ws) + 2 * (long)e);
    float* dinv = (float*)(tmp + e);
    int* rowptr = (int*)(dinv + n);
    int* bbase = rowptr + n + 1;
    int* bcnt = bbase + NB + 1;
    int* gcur = bcnt + NB * 16;
    float* agg1 = (float*)(gcur + NB * 16);
    float* h = agg1 + (long)n * 40;
    float* xl2_32 = agg1;                 // overlay: agg1 dead after linear1
    __half* sh16 = (__half*)tmp;          // overlay: tmp dead after part2

    const int B = 256;
    auto cdiv = [](long a, long b) { return (int)((a + b - 1) / b); };
    const int egrid = cdiv(e, EB);

    // ---- CSR build (shared by both layers) ----
    zero_small_k<<<cdiv(NB * 16, B), B, 0, stream>>>(bcnt, NB * 16);
    bcount_k<<<egrid, B, 0, stream>>>(dstp, bcnt, e, NB);
    bscan_k<<<1, 64, 0, stream>>>(bcnt, bbase, gcur, NB, e);
    part1_k<<<egrid, B, 0, stream>>>(srcp, dstp, ew, gcur, tmp, e, NB);
    part2_k<<<NB, CNODES, 0, stream>>>(tmp, bbase, dinv, rowptr, csr, n, e, NB);

    // ---- x -> fp16 (dinv-folded, padded rows) ----
    tohalf_k<<<cdiv((long)n * 5, B), B, 0, stream>>>(x, dinv, sh16, n);

    // ---- layer 1: agg1 = A_norm @ x, h = relu(agg1 @ W1 + b1) ----
    gather40_k<false><<<cdiv((long)n * 64, B), B, 0, stream>>>(rowptr, csr, sh16, x, dinv, nullptr, agg1, n);
    linear_k<40, 64, true, false><<<2048, B, 0, stream>>>(agg1, W1, b1, h, nullptr, nullptr, n);

    // ---- layer 2: xl2 = h @ W2 (f32 + dinv-folded fp16), out = A_norm @ xl2 + b2 ----
    linear_k<64, 40, false, true><<<2048, B, 0, stream>>>(h, W2, nullptr, xl2_32, sh16, dinv, n);
    gather40_k<true><<<cdiv((long)n * 64, B), B, 0, stream>>>(rowptr, csr, sh16, xl2_32, dinv, b2, out, n);
}

// Round 13
// 310.397 us; speedup vs baseline: 3.7140x; 1.0335x over previous
//
#include <hip/hip_runtime.h>
#include <hip/hip_fp16.h>

// fixed-point scale for weighted-degree accumulation (2^25)
#define FIX 33554432.0f
#define FIXINV (1.0f / 33554432.0f)

typedef unsigned long long ull;

#define EB 1024     // edges per block in bcount/part1
#define CSH 9       // bucket = 512 dst nodes
#define CNODES 512
#define MAXNB 256   // static LDS histogram capacity (NB=196 here)

// ---------------- tiny zero ----------------
__global__ void zero_small_k(int* p, int total) {
    int i = blockIdx.x * blockDim.x + threadIdx.x;
    if (i < total) p[i] = 0;
}

// ---------------- bucket histogram: LDS hist -> 1 global atomic per (block,bucket) ----------------
__global__ void bcount_k(const int* __restrict__ dst, int* __restrict__ bcnt, int e, int NB) {
    __shared__ int lh[MAXNB];
    for (int i = threadIdx.x; i < NB; i += blockDim.x) lh[i] = 0;
    __syncthreads();
    int base = blockIdx.x * EB + threadIdx.x * 4;
    if (base + 3 < e) {
        int4 d4 = *reinterpret_cast<const int4*>(dst + base);
        atomicAdd(&lh[d4.x >> CSH], 1);
        atomicAdd(&lh[d4.y >> CSH], 1);
        atomicAdd(&lh[d4.z >> CSH], 1);
        atomicAdd(&lh[d4.w >> CSH], 1);
    } else {
        for (int i = base; i < e && i < base + 4; ++i) atomicAdd(&lh[dst[i] >> CSH], 1);
    }
    __syncthreads();
    for (int i = threadIdx.x; i < NB; i += blockDim.x) {
        int c = lh[i];
        if (c) atomicAdd(&bcnt[i * 16], c);
    }
}

// ---------------- exclusive scan of NB bucket counts (tiny, serial) ----------------
__global__ void bscan_k(const int* __restrict__ bcnt, int* __restrict__ bbase,
                        int* __restrict__ gcur, int NB, int e) {
    if (threadIdx.x == 0) {
        int run = 0;
        for (int i = 0; i < NB; ++i) {
            bbase[i] = run;
            gcur[i * 16] = run;
            run += bcnt[i * 16];
        }
        bbase[NB] = e;
    }
}

// ---------------- phase 1: LDS-staged bucket partition ----------------
// rec = ewbits[57:26] | src[25:9] | (dst&511)[8:0]
__global__ void part1_k(const int* __restrict__ src, const int* __restrict__ dst,
                        const float* __restrict__ ew, int* gcur, ull* __restrict__ tmp,
                        int e, int NB) {
    __shared__ int lh[MAXNB];
    __shared__ int lb[MAXNB];
    for (int i = threadIdx.x; i < NB; i += blockDim.x) lh[i] = 0;
    __syncthreads();
    int base = blockIdx.x * EB + threadIdx.x * 4;
    bool full = (blockIdx.x + 1) * EB <= e;  // block-uniform
    int bk[4], ls[4];
    ull rec[4];
    bool val[4];
    if (full) {
        int4 s4 = *reinterpret_cast<const int4*>(src + base);
        int4 d4 = *reinterpret_cast<const int4*>(dst + base);
        float4 e4 = *reinterpret_cast<const float4*>(ew + base);
        int s[4] = {s4.x, s4.y, s4.z, s4.w};
        int d[4] = {d4.x, d4.y, d4.z, d4.w};
        float ev[4] = {e4.x, e4.y, e4.z, e4.w};
#pragma unroll
        for (int j = 0; j < 4; ++j) {
            val[j] = true;
            bk[j] = d[j] >> CSH;
            rec[j] = ((ull)__float_as_uint(ev[j]) << 26) | ((ull)(unsigned)s[j] << 9) |
                     (ull)(unsigned)(d[j] & (CNODES - 1));
            ls[j] = atomicAdd(&lh[bk[j]], 1);
        }
    } else {
#pragma unroll
        for (int j = 0; j < 4; ++j) {
            int i = base + j;
            val[j] = (i < e);
            int s = val[j] ? src[i] : 0;
            int d = val[j] ? dst[i] : 0;
            float ev = val[j] ? ew[i] : 0.0f;
            bk[j] = d >> CSH;
            rec[j] = ((ull)__float_as_uint(ev) << 26) | ((ull)(unsigned)s << 9) |
                     (ull)(unsigned)(d & (CNODES - 1));
            ls[j] = val[j] ? atomicAdd(&lh[bk[j]], 1) : 0;
        }
    }
    __syncthreads();
    for (int i = threadIdx.x; i < NB; i += blockDim.x) {
        int c = lh[i];
        lb[i] = c ? atomicAdd(&gcur[i * 16], c) : 0;
    }
    __syncthreads();
#pragma unroll
    for (int j = 0; j < 4; ++j)
        if (val[j]) tmp[lb[bk[j]] + ls[j]] = rec[j];
}

// ---------------- phase 2: per-bucket cnt/deg/dinv/rowptr + node-sorted CSR ----------------
__global__ __launch_bounds__(CNODES) void part2_k(const ull* __restrict__ tmp,
                                                  const int* __restrict__ bbase,
                                                  float* __restrict__ dinv,
                                                  int* __restrict__ rowptr,
                                                  uint2* __restrict__ csr,
                                                  int n, int e, int NB) {
    __shared__ ull ldc[CNODES];   // hi32: cnt, lo32: fixed-point deg
    __shared__ int sc[CNODES];    // scan buffer, then global cursor
    int b = blockIdx.x;
    int tid = threadIdx.x;
    ldc[tid] = 0;
    __syncthreads();
    int beg = bbase[b], end = bbase[b + 1];
    // pass A: count + weighted degree (deterministic fixed-point)
    for (int i = beg + tid; i < end; i += CNODES) {
        ull rec = tmp[i];
        int dlo = (int)(rec & (CNODES - 1));
        float ewv = __uint_as_float((unsigned)(rec >> 26));
        atomicAdd(&ldc[dlo], (1ULL << 32) | (ull)__float2uint_rn(ewv * FIX));
    }
    __syncthreads();
    ull v = ldc[tid];
    int cnt = (int)(v >> 32);
    int node = b * CNODES + tid;
    if (node < n) {
        float d = (float)(unsigned)((unsigned)(v & 0xffffffffu) + (1u << 25)) * FIXINV;
        dinv[node] = rsqrtf(d);  // d >= 1 always
    }
    // inclusive scan of cnt over CNODES threads (Hillis-Steele)
    sc[tid] = cnt;
    __syncthreads();
    for (int off = 1; off < CNODES; off <<= 1) {
        int x = (tid >= off) ? sc[tid - off] : 0;
        __syncthreads();
        sc[tid] += x;
        __syncthreads();
    }
    int slotbase = beg + sc[tid] - cnt;  // global CSR base for this node
    if (node < n) rowptr[node] = slotbase;
    if (b == NB - 1 && tid == 0) rowptr[n] = e;
    __syncthreads();
    sc[tid] = slotbase;  // reuse as cursor
    __syncthreads();
    // pass B: scatter into node-sorted CSR (records L2-resident from pass A)
    for (int i = beg + tid; i < end; i += CNODES) {
        ull rec = tmp[i];
        int dlo = (int)(rec & (CNODES - 1));
        unsigned s = (unsigned)((rec >> 9) & 0x1FFFF);
        unsigned ewb = (unsigned)(rec >> 26);
        int slot = atomicAdd(&sc[dlo], 1);
        csr[slot] = make_uint2(s, ewb);
    }
}

// ---------------- x -> fp16 rows at stride 40 (80B rows, 16B-aligned), dinv-folded ----------------
__global__ void tohalf_k(const float* __restrict__ x, const float* __restrict__ dinv,
                         __half* __restrict__ out, int n) {
    long gid = (long)blockIdx.x * blockDim.x + threadIdx.x;
    if (gid >= (long)n * 5) return;
    int row = (int)(gid / 5), c = (int)(gid % 5);
    float di = dinv[row];
    const float4* src = reinterpret_cast<const float4*>(x + (long)row * 40 + c * 8);
    float4 a = src[0], bb = src[1];
    __half2* dst = reinterpret_cast<__half2*>(out + (long)row * 40 + c * 8);
    dst[0] = __floats2half2_rn(di * a.x, di * a.y);
    dst[1] = __floats2half2_rn(di * a.z, di * a.w);
    dst[2] = __floats2half2_rn(di * bb.x, di * bb.y);
    dst[3] = __floats2half2_rn(di * bb.z, di * bb.w);
}

// ---------------- dense linear, wave-per-node: W in VGPRs, x row via SMEM ----------------
// y[n,C] = x[n,K] @ W[K,C]; 4 independent accumulators break the FMA dependence chain
template <int K, int C, bool BIAS_RELU, bool DUAL16>
__global__ __launch_bounds__(256) void linear_k(const float* __restrict__ x,
                                                const float* __restrict__ W,
                                                const float* __restrict__ b,
                                                float* __restrict__ y,
                                                __half* __restrict__ y16,
                                                const float* __restrict__ dinv, int n) {
    int lane = threadIdx.x & 63;
    int wid = blockIdx.x * (blockDim.x >> 6) + (threadIdx.x >> 6);
    int nwaves = gridDim.x * (blockDim.x >> 6);
    float wreg[K];
#pragma unroll
    for (int k = 0; k < K; ++k) wreg[k] = (lane < C) ? W[k * C + lane] : 0.0f;
    float bias = (BIAS_RELU && lane < C) ? b[lane] : 0.0f;
    for (int node = wid; node < n; node += nwaves) {
        int un = __builtin_amdgcn_readfirstlane(node);  // force SGPR base -> s_load row
        const float* xr = x + (long)un * K;
        float a0 = 0.0f, a1 = 0.0f, a2 = 0.0f, a3 = 0.0f;
#pragma unroll
        for (int k = 0; k < K; k += 4) {
            a0 = fmaf(xr[k + 0], wreg[k + 0], a0);
            a1 = fmaf(xr[k + 1], wreg[k + 1], a1);
            a2 = fmaf(xr[k + 2], wreg[k + 2], a2);
            a3 = fmaf(xr[k + 3], wreg[k + 3], a3);
        }
        float acc = (a0 + a1) + (a2 + a3);
        if (BIAS_RELU) acc = fmaxf(acc + bias, 0.0f);
        if (lane < C) {
            y[(long)un * C + lane] = acc;
            if (DUAL16) y16[(long)un * 40 + lane] = __float2half(dinv[un] * acc);
        }
    }
}

// ---------------- gather at C=40: wave/node, lane=channel, stride-40 fp16 rows, 8-deep ----------------
// out = dinv[d] * sum(ew * feat16'[src]) + dinv[d]^2 * selfF[d] (+ b);  feat16' = dinv*feat
template <bool ADD_BIAS>
__global__ void gather40_k(const int* __restrict__ rowptr, const uint2* __restrict__ csr,
                           const __half* __restrict__ feat16, const float* __restrict__ selfF,
                           const float* __restrict__ dinv, const float* __restrict__ b,
                           float* __restrict__ out, int n) {
    int node = (int)(((long)blockIdx.x * blockDim.x + threadIdx.x) >> 6);
    int lane = threadIdx.x & 63;
    if (node >= n) return;
    int beg = __builtin_amdgcn_readfirstlane(rowptr[node]);
    int end = __builtin_amdgcn_readfirstlane(rowptr[node + 1]);
    if (lane >= 40) return;
    float accE = 0.0f;
    int t = beg;
    // peel to even t so csr+t is 16B-aligned for uint4 loads
    if (t < end && (t & 1)) {
        uint2 q = csr[t];
        accE = fmaf(__uint_as_float(q.y), __half2float(feat16[(long)q.x * 40 + lane]), accE);
        ++t;
    }
    for (; t + 7 < end; t += 8) {
        uint4 p0 = *reinterpret_cast<const uint4*>(csr + t);
        uint4 p1 = *reinterpret_cast<const uint4*>(csr + t + 2);
        uint4 p2 = *reinterpret_cast<const uint4*>(csr + t + 4);
        uint4 p3 = *reinterpret_cast<const uint4*>(csr + t + 6);
        float v0 = __half2float(feat16[(long)p0.x * 40 + lane]);
        float v1 = __half2float(feat16[(long)p0.z * 40 + lane]);
        float v2 = __half2float(feat16[(long)p1.x * 40 + lane]);
        float v3 = __half2float(feat16[(long)p1.z * 40 + lane]);
        float v4 = __half2float(feat16[(long)p2.x * 40 + lane]);
        float v5 = __half2float(feat16[(long)p2.z * 40 + lane]);
        float v6 = __half2float(feat16[(long)p3.x * 40 + lane]);
        float v7 = __half2float(feat16[(long)p3.z * 40 + lane]);
        accE = fmaf(__uint_as_float(p0.y), v0, accE);
        accE = fmaf(__uint_as_float(p0.w), v1, accE);
        accE = fmaf(__uint_as_float(p1.y), v2, accE);
        accE = fmaf(__uint_as_float(p1.w), v3, accE);
        accE = fmaf(__uint_as_float(p2.y), v4, accE);
        accE = fmaf(__uint_as_float(p2.w), v5, accE);
        accE = fmaf(__uint_as_float(p3.y), v6, accE);
        accE = fmaf(__uint_as_float(p3.w), v7, accE);
    }
    for (; t + 1 < end; t += 2) {
        uint4 p = *reinterpret_cast<const uint4*>(csr + t);
        float v0 = __half2float(feat16[(long)p.x * 40 + lane]);
        float v1 = __half2float(feat16[(long)p.z * 40 + lane]);
        accE = fmaf(__uint_as_float(p.y), v0, accE);
        accE = fmaf(__uint_as_float(p.w), v1, accE);
    }
    if (t < end) {
        uint2 q = csr[t];
        accE = fmaf(__uint_as_float(q.y), __half2float(feat16[(long)q.x * 40 + lane]), accE);
    }
    float di = dinv[node];
    float r = di * accE + di * di * selfF[(long)node * 40 + lane];
    if (ADD_BIAS) r += b[lane];
    out[(long)node * 40 + lane] = r;
}

extern "C" void kernel_launch(void* const* d_in, const int* in_sizes, int n_in,
                              void* d_out, int out_size, void* d_ws, size_t ws_size,
                              hipStream_t stream) {
    const float* x = (const float*)d_in[0];
    const int* ei = (const int*)d_in[1];
    const float* ew = (const float*)d_in[2];
    const float* W1 = (const float*)d_in[3];
    const float* b1 = (const float*)d_in[4];
    const float* W2 = (const float*)d_in[5];
    const float* b2 = (const float*)d_in[6];
    float* out = (float*)d_out;

    const int n = in_sizes[0] / 40;   // 100000
    const int e = in_sizes[2];        // 1600000
    const int* srcp = ei;
    const int* dstp = ei + e;
    const int NB = (n + CNODES - 1) >> CSH;  // 196 buckets

    // ws layout (4B units):
    // csr[2e] | tmp[2e] | dinv[n] | rowptr[n+1] | bbase[NB+1] | bcnt[NB*16] | gcur[NB*16] |
    // agg1/xl2_32[n*40] | h[n*64]
    // sh16 (40n halves = 20n words < 2e words) overlays tmp (dead after part2)
    uint2* csr = (uint2*)d_ws;
    ull* tmp = (ull*)(((int*)d_ws) + 2 * (long)e);
    float* dinv = (float*)(tmp + e);
    int* rowptr = (int*)(dinv + n);
    int* bbase = rowptr + n + 1;
    int* bcnt = bbase + NB + 1;
    int* gcur = bcnt + NB * 16;
    float* agg1 = (float*)(gcur + NB * 16);
    float* h = agg1 + (long)n * 40;
    float* xl2_32 = agg1;                 // overlay: agg1 dead after linear1
    __half* sh16 = (__half*)tmp;          // overlay: tmp dead after part2

    const int B = 256;
    auto cdiv = [](long a, long b) { return (int)((a + b - 1) / b); };
    const int egrid = cdiv(e, EB);

    // ---- CSR build (shared by both layers) ----
    zero_small_k<<<cdiv(NB * 16, B), B, 0, stream>>>(bcnt, NB * 16);
    bcount_k<<<egrid, B, 0, stream>>>(dstp, bcnt, e, NB);
    bscan_k<<<1, 64, 0, stream>>>(bcnt, bbase, gcur, NB, e);
    part1_k<<<egrid, B, 0, stream>>>(srcp, dstp, ew, gcur, tmp, e, NB);
    part2_k<<<NB, CNODES, 0, stream>>>(tmp, bbase, dinv, rowptr, csr, n, e, NB);

    // ---- x -> fp16 (dinv-folded, stride-40 rows) ----
    tohalf_k<<<cdiv((long)n * 5, B), B, 0, stream>>>(x, dinv, sh16, n);

    // ---- layer 1: agg1 = A_norm @ x, h = relu(agg1 @ W1 + b1) ----
    gather40_k<false><<<cdiv((long)n * 64, B), B, 0, stream>>>(rowptr, csr, sh16, x, dinv, nullptr, agg1, n);
    linear_k<40, 64, true, false><<<2048, B, 0, stream>>>(agg1, W1, b1, h, nullptr, nullptr, n);

    // ---- layer 2: xl2 = h @ W2 (f32 + dinv-folded fp16), out = A_norm @ xl2 + b2 ----
    linear_k<64, 40, false, true><<<2048, B, 0, stream>>>(h, W2, nullptr, xl2_32, sh16, dinv, n);
    gather40_k<true><<<cdiv((long)n * 64, B), B, 0, stream>>>(rowptr, csr, sh16, xl2_32, dinv, b2, out, n);
}

// Round 14
// 298.302 us; speedup vs baseline: 3.8646x; 1.0405x over previous
//
#include <hip/hip_runtime.h>
#include <hip/hip_fp16.h>

// fixed-point scale for weighted-degree accumulation (2^25)
#define FIX 33554432.0f
#define FIXINV (1.0f / 33554432.0f)

typedef unsigned long long ull;

#define EB 1024     // edges per block in bcount/part1
#define CSH 9       // bucket = 512 dst nodes
#define CNODES 512
#define MAXNB 256   // static LDS histogram capacity (NB=196 here)

// ---------------- tiny zero ----------------
__global__ void zero_small_k(int* p, int total) {
    int i = blockIdx.x * blockDim.x + threadIdx.x;
    if (i < total) p[i] = 0;
}

// ---------------- bucket histogram: LDS hist -> 1 global atomic per (block,bucket) ----------------
__global__ void bcount_k(const int* __restrict__ dst, int* __restrict__ bcnt, int e, int NB) {
    __shared__ int lh[MAXNB];
    for (int i = threadIdx.x; i < NB; i += blockDim.x) lh[i] = 0;
    __syncthreads();
    int base = blockIdx.x * EB + threadIdx.x * 4;
    if (base + 3 < e) {
        int4 d4 = *reinterpret_cast<const int4*>(dst + base);
        atomicAdd(&lh[d4.x >> CSH], 1);
        atomicAdd(&lh[d4.y >> CSH], 1);
        atomicAdd(&lh[d4.z >> CSH], 1);
        atomicAdd(&lh[d4.w >> CSH], 1);
    } else {
        for (int i = base; i < e && i < base + 4; ++i) atomicAdd(&lh[dst[i] >> CSH], 1);
    }
    __syncthreads();
    for (int i = threadIdx.x; i < NB; i += blockDim.x) {
        int c = lh[i];
        if (c) atomicAdd(&bcnt[i * 16], c);
    }
}

// ---------------- exclusive scan of NB bucket counts (tiny, serial) ----------------
__global__ void bscan_k(const int* __restrict__ bcnt, int* __restrict__ bbase,
                        int* __restrict__ gcur, int NB, int e) {
    if (threadIdx.x == 0) {
        int run = 0;
        for (int i = 0; i < NB; ++i) {
            bbase[i] = run;
            gcur[i * 16] = run;
            run += bcnt[i * 16];
        }
        bbase[NB] = e;
    }
}

// ---------------- phase 1: LDS-staged bucket partition ----------------
// rec = ewbits[57:26] | src[25:9] | (dst&511)[8:0]
__global__ void part1_k(const int* __restrict__ src, const int* __restrict__ dst,
                        const float* __restrict__ ew, int* gcur, ull* __restrict__ tmp,
                        int e, int NB) {
    __shared__ int lh[MAXNB];
    __shared__ int lb[MAXNB];
    for (int i = threadIdx.x; i < NB; i += blockDim.x) lh[i] = 0;
    __syncthreads();
    int base = blockIdx.x * EB + threadIdx.x * 4;
    bool full = (blockIdx.x + 1) * EB <= e;  // block-uniform
    int bk[4], ls[4];
    ull rec[4];
    bool val[4];
    if (full) {
        int4 s4 = *reinterpret_cast<const int4*>(src + base);
        int4 d4 = *reinterpret_cast<const int4*>(dst + base);
        float4 e4 = *reinterpret_cast<const float4*>(ew + base);
        int s[4] = {s4.x, s4.y, s4.z, s4.w};
        int d[4] = {d4.x, d4.y, d4.z, d4.w};
        float ev[4] = {e4.x, e4.y, e4.z, e4.w};
#pragma unroll
        for (int j = 0; j < 4; ++j) {
            val[j] = true;
            bk[j] = d[j] >> CSH;
            rec[j] = ((ull)__float_as_uint(ev[j]) << 26) | ((ull)(unsigned)s[j] << 9) |
                     (ull)(unsigned)(d[j] & (CNODES - 1));
            ls[j] = atomicAdd(&lh[bk[j]], 1);
        }
    } else {
#pragma unroll
        for (int j = 0; j < 4; ++j) {
            int i = base + j;
            val[j] = (i < e);
            int s = val[j] ? src[i] : 0;
            int d = val[j] ? dst[i] : 0;
            float ev = val[j] ? ew[i] : 0.0f;
            bk[j] = d >> CSH;
            rec[j] = ((ull)__float_as_uint(ev) << 26) | ((ull)(unsigned)s << 9) |
                     (ull)(unsigned)(d & (CNODES - 1));
            ls[j] = val[j] ? atomicAdd(&lh[bk[j]], 1) : 0;
        }
    }
    __syncthreads();
    for (int i = threadIdx.x; i < NB; i += blockDim.x) {
        int c = lh[i];
        lb[i] = c ? atomicAdd(&gcur[i * 16], c) : 0;
    }
    __syncthreads();
#pragma unroll
    for (int j = 0; j < 4; ++j)
        if (val[j]) tmp[lb[bk[j]] + ls[j]] = rec[j];
}

// ---------------- phase 2: per-bucket cnt/deg/dinv/rowptr + node-sorted CSR ----------------
__global__ __launch_bounds__(CNODES) void part2_k(const ull* __restrict__ tmp,
                                                  const int* __restrict__ bbase,
                                                  float* __restrict__ dinv,
                                                  int* __restrict__ rowptr,
                                                  uint2* __restrict__ csr,
                                                  int n, int e, int NB) {
    __shared__ ull ldc[CNODES];   // hi32: cnt, lo32: fixed-point deg
    __shared__ int sc[CNODES];    // scan buffer, then global cursor
    int b = blockIdx.x;
    int tid = threadIdx.x;
    ldc[tid] = 0;
    __syncthreads();
    int beg = bbase[b], end = bbase[b + 1];
    // pass A: count + weighted degree (deterministic fixed-point)
    for (int i = beg + tid; i < end; i += CNODES) {
        ull rec = tmp[i];
        int dlo = (int)(rec & (CNODES - 1));
        float ewv = __uint_as_float((unsigned)(rec >> 26));
        atomicAdd(&ldc[dlo], (1ULL << 32) | (ull)__float2uint_rn(ewv * FIX));
    }
    __syncthreads();
    ull v = ldc[tid];
    int cnt = (int)(v >> 32);
    int node = b * CNODES + tid;
    if (node < n) {
        float d = (float)(unsigned)((unsigned)(v & 0xffffffffu) + (1u << 25)) * FIXINV;
        dinv[node] = rsqrtf(d);  // d >= 1 always
    }
    // inclusive scan of cnt over CNODES threads (Hillis-Steele)
    sc[tid] = cnt;
    __syncthreads();
    for (int off = 1; off < CNODES; off <<= 1) {
        int x = (tid >= off) ? sc[tid - off] : 0;
        __syncthreads();
        sc[tid] += x;
        __syncthreads();
    }
    int slotbase = beg + sc[tid] - cnt;  // global CSR base for this node
    if (node < n) rowptr[node] = slotbase;
    if (b == NB - 1 && tid == 0) rowptr[n] = e;
    __syncthreads();
    sc[tid] = slotbase;  // reuse as cursor
    __syncthreads();
    // pass B: scatter into node-sorted CSR (records L2-resident from pass A)
    for (int i = beg + tid; i < end; i += CNODES) {
        ull rec = tmp[i];
        int dlo = (int)(rec & (CNODES - 1));
        unsigned s = (unsigned)((rec >> 9) & 0x1FFFF);
        unsigned ewb = (unsigned)(rec >> 26);
        int slot = atomicAdd(&sc[dlo], 1);
        csr[slot] = make_uint2(s, ewb);
    }
}

// ---------------- x -> fp16 rows at stride 40 (80B rows, 16B-aligned), dinv-folded ----------------
__global__ void tohalf_k(const float* __restrict__ x, const float* __restrict__ dinv,
                         __half* __restrict__ out, int n) {
    long gid = (long)blockIdx.x * blockDim.x + threadIdx.x;
    if (gid >= (long)n * 5) return;
    int row = (int)(gid / 5), c = (int)(gid % 5);
    float di = dinv[row];
    const float4* src = reinterpret_cast<const float4*>(x + (long)row * 40 + c * 8);
    float4 a = src[0], bb = src[1];
    __half2* dst = reinterpret_cast<__half2*>(out + (long)row * 40 + c * 8);
    dst[0] = __floats2half2_rn(di * a.x, di * a.y);
    dst[1] = __floats2half2_rn(di * a.z, di * a.w);
    dst[2] = __floats2half2_rn(di * bb.x, di * bb.y);
    dst[3] = __floats2half2_rn(di * bb.z, di * bb.w);
}

// ---------------- dense linear, wave-per-node: W in VGPRs, coalesced row + readlane ----------------
// y[n,C] = x[n,K] @ W[K,C]; lane l loads x[node*K+l]; K-dot via readlane broadcast (SGPR operand)
template <int K, int C, bool BIAS_RELU, bool DUAL16>
__global__ __launch_bounds__(256) void linear_k(const float* __restrict__ x,
                                                const float* __restrict__ W,
                                                const float* __restrict__ b,
                                                float* __restrict__ y,
                                                __half* __restrict__ y16,
                                                const float* __restrict__ dinv, int n) {
    int lane = threadIdx.x & 63;
    int wid = blockIdx.x * (blockDim.x >> 6) + (threadIdx.x >> 6);
    int nwaves = gridDim.x * (blockDim.x >> 6);
    float wreg[K];
#pragma unroll
    for (int k = 0; k < K; ++k) wreg[k] = (lane < C) ? W[k * C + lane] : 0.0f;
    float bias = (BIAS_RELU && lane < C) ? b[lane] : 0.0f;
    for (int node = wid; node < n; node += nwaves) {
        // ONE coalesced row load per node; all 64 lanes stay active (readlane needs them)
        float xv = (lane < K) ? x[(long)node * K + lane] : 0.0f;
        unsigned xu = __float_as_uint(xv);
        float a0 = 0.0f, a1 = 0.0f, a2 = 0.0f, a3 = 0.0f;
#pragma unroll
        for (int k = 0; k < K; k += 4) {
            a0 = fmaf(__uint_as_float(__builtin_amdgcn_readlane(xu, k + 0)), wreg[k + 0], a0);
            a1 = fmaf(__uint_as_float(__builtin_amdgcn_readlane(xu, k + 1)), wreg[k + 1], a1);
            a2 = fmaf(__uint_as_float(__builtin_amdgcn_readlane(xu, k + 2)), wreg[k + 2], a2);
            a3 = fmaf(__uint_as_float(__builtin_amdgcn_readlane(xu, k + 3)), wreg[k + 3], a3);
        }
        float acc = (a0 + a1) + (a2 + a3);
        if (BIAS_RELU) acc = fmaxf(acc + bias, 0.0f);
        if (lane < C) {
            y[(long)node * C + lane] = acc;
            if (DUAL16) y16[(long)node * 40 + lane] = __float2half(dinv[node] * acc);
        }
    }
}

// ---------------- gather at C=40: wave/node, lane=channel, stride-40 fp16 rows, 8-deep ----------------
// out = dinv[d] * sum(ew * feat16'[src]) + dinv[d]^2 * selfF[d] (+ b);  feat16' = dinv*feat
template <bool ADD_BIAS>
__global__ void gather40_k(const int* __restrict__ rowptr, const uint2* __restrict__ csr,
                           const __half* __restrict__ feat16, const float* __restrict__ selfF,
                           const float* __restrict__ dinv, const float* __restrict__ b,
                           float* __restrict__ out, int n) {
    int node = (int)(((long)blockIdx.x * blockDim.x + threadIdx.x) >> 6);
    int lane = threadIdx.x & 63;
    if (node >= n) return;
    int beg = __builtin_amdgcn_readfirstlane(rowptr[node]);
    int end = __builtin_amdgcn_readfirstlane(rowptr[node + 1]);
    if (lane >= 40) return;
    float accE = 0.0f;
    int t = beg;
    // peel to even t so csr+t is 16B-aligned for uint4 loads
    if (t < end && (t & 1)) {
        uint2 q = csr[t];
        accE = fmaf(__uint_as_float(q.y), __half2float(feat16[(long)q.x * 40 + lane]), accE);
        ++t;
    }
    for (; t + 7 < end; t += 8) {
        uint4 p0 = *reinterpret_cast<const uint4*>(csr + t);
        uint4 p1 = *reinterpret_cast<const uint4*>(csr + t + 2);
        uint4 p2 = *reinterpret_cast<const uint4*>(csr + t + 4);
        uint4 p3 = *reinterpret_cast<const uint4*>(csr + t + 6);
        float v0 = __half2float(feat16[(long)p0.x * 40 + lane]);
        float v1 = __half2float(feat16[(long)p0.z * 40 + lane]);
        float v2 = __half2float(feat16[(long)p1.x * 40 + lane]);
        float v3 = __half2float(feat16[(long)p1.z * 40 + lane]);
        float v4 = __half2float(feat16[(long)p2.x * 40 + lane]);
        float v5 = __half2float(feat16[(long)p2.z * 40 + lane]);
        float v6 = __half2float(feat16[(long)p3.x * 40 + lane]);
        float v7 = __half2float(feat16[(long)p3.z * 40 + lane]);
        accE = fmaf(__uint_as_float(p0.y), v0, accE);
        accE = fmaf(__uint_as_float(p0.w), v1, accE);
        accE = fmaf(__uint_as_float(p1.y), v2, accE);
        accE = fmaf(__uint_as_float(p1.w), v3, accE);
        accE = fmaf(__uint_as_float(p2.y), v4, accE);
        accE = fmaf(__uint_as_float(p2.w), v5, accE);
        accE = fmaf(__uint_as_float(p3.y), v6, accE);
        accE = fmaf(__uint_as_float(p3.w), v7, accE);
    }
    for (; t + 1 < end; t += 2) {
        uint4 p = *reinterpret_cast<const uint4*>(csr + t);
        float v0 = __half2float(feat16[(long)p.x * 40 + lane]);
        float v1 = __half2float(feat16[(long)p.z * 40 + lane]);
        accE = fmaf(__uint_as_float(p.y), v0, accE);
        accE = fmaf(__uint_as_float(p.w), v1, accE);
    }
    if (t < end) {
        uint2 q = csr[t];
        accE = fmaf(__uint_as_float(q.y), __half2float(feat16[(long)q.x * 40 + lane]), accE);
    }
    float di = dinv[node];
    float r = di * accE + di * di * selfF[(long)node * 40 + lane];
    if (ADD_BIAS) r += b[lane];
    out[(long)node * 40 + lane] = r;
}

extern "C" void kernel_launch(void* const* d_in, const int* in_sizes, int n_in,
                              void* d_out, int out_size, void* d_ws, size_t ws_size,
                              hipStream_t stream) {
    const float* x = (const float*)d_in[0];
    const int* ei = (const int*)d_in[1];
    const float* ew = (const float*)d_in[2];
    const float* W1 = (const float*)d_in[3];
    const float* b1 = (const float*)d_in[4];
    const float* W2 = (const float*)d_in[5];
    const float* b2 = (const float*)d_in[6];
    float* out = (float*)d_out;

    const int n = in_sizes[0] / 40;   // 100000
    const int e = in_sizes[2];        // 1600000
    const int* srcp = ei;
    const int* dstp = ei + e;
    const int NB = (n + CNODES - 1) >> CSH;  // 196 buckets

    // ws layout (4B units):
    // csr[2e] | tmp[2e] | dinv[n] | rowptr[n+1] | bbase[NB+1] | bcnt[NB*16] | gcur[NB*16] |
    // agg1/xl2_32[n*40] | h[n*64]
    // sh16 (40n halves = 20n words < 2e words) overlays tmp (dead after part2)
    uint2* csr = (uint2*)d_ws;
    ull* tmp = (ull*)(((int*)d_ws) + 2 * (long)e);
    float* dinv = (float*)(tmp + e);
    int* rowptr = (int*)(dinv + n);
    int* bbase = rowptr + n + 1;
    int* bcnt = bbase + NB + 1;
    int* gcur = bcnt + NB * 16;
    float* agg1 = (float*)(gcur + NB * 16);
    float* h = agg1 + (long)n * 40;
    float* xl2_32 = agg1;                 // overlay: agg1 dead after linear1
    __half* sh16 = (__half*)tmp;          // overlay: tmp dead after part2

    const int B = 256;
    auto cdiv = [](long a, long b) { return (int)((a + b - 1) / b); };
    const int egrid = cdiv(e, EB);

    // ---- CSR build (shared by both layers) ----
    zero_small_k<<<cdiv(NB * 16, B), B, 0, stream>>>(bcnt, NB * 16);
    bcount_k<<<egrid, B, 0, stream>>>(dstp, bcnt, e, NB);
    bscan_k<<<1, 64, 0, stream>>>(bcnt, bbase, gcur, NB, e);
    part1_k<<<egrid, B, 0, stream>>>(srcp, dstp, ew, gcur, tmp, e, NB);
    part2_k<<<NB, CNODES, 0, stream>>>(tmp, bbase, dinv, rowptr, csr, n, e, NB);

    // ---- x -> fp16 (dinv-folded, stride-40 rows) ----
    tohalf_k<<<cdiv((long)n * 5, B), B, 0, stream>>>(x, dinv, sh16, n);

    // ---- layer 1: agg1 = A_norm @ x, h = relu(agg1 @ W1 + b1) ----
    gather40_k<false><<<cdiv((long)n * 64, B), B, 0, stream>>>(rowptr, csr, sh16, x, dinv, nullptr, agg1, n);
    linear_k<40, 64, true, false><<<2048, B, 0, stream>>>(agg1, W1, b1, h, nullptr, nullptr, n);

    // ---- layer 2: xl2 = h @ W2 (f32 + dinv-folded fp16), out = A_norm @ xl2 + b2 ----
    linear_k<64, 40, false, true><<<2048, B, 0, stream>>>(h, W2, nullptr, xl2_32, sh16, dinv, n);
    gather40_k<true><<<cdiv((long)n * 64, B), B, 0, stream>>>(rowptr, csr, sh16, xl2_32, dinv, b2, out, n);
}

// Round 15
// 279.986 us; speedup vs baseline: 4.1174x; 1.0654x over previous
//
#include <hip/hip_runtime.h>
#include <hip/hip_fp16.h>

// fixed-point scale for weighted-degree accumulation (2^25)
#define FIX 33554432.0f
#define FIXINV (1.0f / 33554432.0f)

typedef unsigned long long ull;

#define EB 1024     // edges per block in bcount/part1 (identical grids => class counts match)
#define CSH 9       // bucket = 512 dst nodes
#define CNODES 512
#define MAXNB 256   // static LDS histogram capacity (NB=196 here)

// ---------------- tiny zero ----------------
__global__ void zero_small_k(int* p, int total) {
    int i = blockIdx.x * blockDim.x + threadIdx.x;
    if (i < total) p[i] = 0;
}

// ---------------- bucket histogram per XCD-class: LDS hist -> 1 atomic per (block,bucket) ----------------
__global__ void bcount_k(const int* __restrict__ dst, int* __restrict__ bcnt, int e, int NB) {
    __shared__ int lh[MAXNB];
    for (int i = threadIdx.x; i < NB; i += blockDim.x) lh[i] = 0;
    __syncthreads();
    int cls = blockIdx.x & 7;
    int base = blockIdx.x * EB + threadIdx.x * 4;
    if (base + 3 < e) {
        int4 d4 = *reinterpret_cast<const int4*>(dst + base);
        atomicAdd(&lh[d4.x >> CSH], 1);
        atomicAdd(&lh[d4.y >> CSH], 1);
        atomicAdd(&lh[d4.z >> CSH], 1);
        atomicAdd(&lh[d4.w >> CSH], 1);
    } else {
        for (int i = base; i < e && i < base + 4; ++i) atomicAdd(&lh[dst[i] >> CSH], 1);
    }
    __syncthreads();
    for (int i = threadIdx.x; i < NB; i += blockDim.x) {
        int c = lh[i];
        if (c) atomicAdd(&bcnt[(i * 8 + cls) * 16], c);
    }
}

// ---------------- serial scan over (bucket-major, class-minor) -> cursors + bucket bases ----------------
__global__ void bscan_k(const int* __restrict__ bcnt, int* __restrict__ bbase,
                        int* __restrict__ gcur, int NB, int e) {
    if (threadIdx.x == 0) {
        int run = 0;
        for (int b = 0; b < NB; ++b) {
            bbase[b] = run;
            for (int x = 0; x < 8; ++x) {
                int idx = (b * 8 + x) * 16;
                gcur[idx] = run;
                run += bcnt[idx];
            }
        }
        bbase[NB] = e;
    }
}

// ---------------- phase 1: LDS-staged bucket partition, per-class cursors (XCD-local) ----------------
// rec = ewbits[57:26] | src[25:9] | (dst&511)[8:0]
__global__ void part1_k(const int* __restrict__ src, const int* __restrict__ dst,
                        const float* __restrict__ ew, int* gcur, ull* __restrict__ tmp,
                        int e, int NB) {
    __shared__ int lh[MAXNB];
    __shared__ int lb[MAXNB];
    for (int i = threadIdx.x; i < NB; i += blockDim.x) lh[i] = 0;
    __syncthreads();
    int cls = blockIdx.x & 7;
    int base = blockIdx.x * EB + threadIdx.x * 4;
    bool full = (blockIdx.x + 1) * EB <= e;  // block-uniform
    int bk[4], ls[4];
    ull rec[4];
    bool val[4];
    if (full) {
        int4 s4 = *reinterpret_cast<const int4*>(src + base);
        int4 d4 = *reinterpret_cast<const int4*>(dst + base);
        float4 e4 = *reinterpret_cast<const float4*>(ew + base);
        int s[4] = {s4.x, s4.y, s4.z, s4.w};
        int d[4] = {d4.x, d4.y, d4.z, d4.w};
        float ev[4] = {e4.x, e4.y, e4.z, e4.w};
#pragma unroll
        for (int j = 0; j < 4; ++j) {
            val[j] = true;
            bk[j] = d[j] >> CSH;
            rec[j] = ((ull)__float_as_uint(ev[j]) << 26) | ((ull)(unsigned)s[j] << 9) |
                     (ull)(unsigned)(d[j] & (CNODES - 1));
            ls[j] = atomicAdd(&lh[bk[j]], 1);
        }
    } else {
#pragma unroll
        for (int j = 0; j < 4; ++j) {
            int i = base + j;
            val[j] = (i < e);
            int s = val[j] ? src[i] : 0;
            int d = val[j] ? dst[i] : 0;
            float ev = val[j] ? ew[i] : 0.0f;
            bk[j] = d >> CSH;
            rec[j] = ((ull)__float_as_uint(ev) << 26) | ((ull)(unsigned)s << 9) |
                     (ull)(unsigned)(d & (CNODES - 1));
            ls[j] = val[j] ? atomicAdd(&lh[bk[j]], 1) : 0;
        }
    }
    __syncthreads();
    for (int i = threadIdx.x; i < NB; i += blockDim.x) {
        int c = lh[i];
        lb[i] = c ? atomicAdd(&gcur[(i * 8 + cls) * 16], c) : 0;
    }
    __syncthreads();
#pragma unroll
    for (int j = 0; j < 4; ++j)
        if (val[j]) tmp[lb[bk[j]] + ls[j]] = rec[j];
}

// ---------------- phase 2: per-bucket cnt/deg/dinv/rowptr + node-sorted CSR ----------------
__global__ __launch_bounds__(CNODES) void part2_k(const ull* __restrict__ tmp,
                                                  const int* __restrict__ bbase,
                                                  float* __restrict__ dinv,
                                                  int* __restrict__ rowptr,
                                                  uint2* __restrict__ csr,
                                                  int n, int e, int NB) {
    __shared__ ull ldc[CNODES];   // hi32: cnt, lo32: fixed-point deg
    __shared__ int sc[CNODES];    // scan buffer, then global cursor
    int b = blockIdx.x;
    int tid = threadIdx.x;
    ldc[tid] = 0;
    __syncthreads();
    int beg = bbase[b], end = bbase[b + 1];
    // pass A: count + weighted degree (deterministic fixed-point)
    for (int i = beg + tid; i < end; i += CNODES) {
        ull rec = tmp[i];
        int dlo = (int)(rec & (CNODES - 1));
        float ewv = __uint_as_float((unsigned)(rec >> 26));
        atomicAdd(&ldc[dlo], (1ULL << 32) | (ull)__float2uint_rn(ewv * FIX));
    }
    __syncthreads();
    ull v = ldc[tid];
    int cnt = (int)(v >> 32);
    int node = b * CNODES + tid;
    if (node < n) {
        float d = (float)(unsigned)((unsigned)(v & 0xffffffffu) + (1u << 25)) * FIXINV;
        dinv[node] = rsqrtf(d);  // d >= 1 always
    }
    // inclusive scan of cnt over CNODES threads (Hillis-Steele)
    sc[tid] = cnt;
    __syncthreads();
    for (int off = 1; off < CNODES; off <<= 1) {
        int x = (tid >= off) ? sc[tid - off] : 0;
        __syncthreads();
        sc[tid] += x;
        __syncthreads();
    }
    int slotbase = beg + sc[tid] - cnt;  // global CSR base for this node
    if (node < n) rowptr[node] = slotbase;
    if (b == NB - 1 && tid == 0) rowptr[n] = e;
    __syncthreads();
    sc[tid] = slotbase;  // reuse as cursor
    __syncthreads();
    // pass B: scatter into node-sorted CSR (records L2-resident from pass A)
    for (int i = beg + tid; i < end; i += CNODES) {
        ull rec = tmp[i];
        int dlo = (int)(rec & (CNODES - 1));
        unsigned s = (unsigned)((rec >> 9) & 0x1FFFF);
        unsigned ewb = (unsigned)(rec >> 26);
        int slot = atomicAdd(&sc[dlo], 1);
        csr[slot] = make_uint2(s, ewb);
    }
}

// ---------------- x -> fp16 rows at stride 40 (80B rows, 16B-aligned), dinv-folded ----------------
__global__ void tohalf_k(const float* __restrict__ x, const float* __restrict__ dinv,
                         __half* __restrict__ out, int n) {
    long gid = (long)blockIdx.x * blockDim.x + threadIdx.x;
    if (gid >= (long)n * 5) return;
    int row = (int)(gid / 5), c = (int)(gid % 5);
    float di = dinv[row];
    const float4* src = reinterpret_cast<const float4*>(x + (long)row * 40 + c * 8);
    float4 a = src[0], bb = src[1];
    __half2* dst = reinterpret_cast<__half2*>(out + (long)row * 40 + c * 8);
    dst[0] = __floats2half2_rn(di * a.x, di * a.y);
    dst[1] = __floats2half2_rn(di * a.z, di * a.w);
    dst[2] = __floats2half2_rn(di * bb.x, di * bb.y);
    dst[3] = __floats2half2_rn(di * bb.z, di * bb.w);
}

// ---------------- dense linear, wave-per-node: W in VGPRs, coalesced row + readlane ----------------
template <int K, int C, bool BIAS_RELU, bool DUAL16>
__global__ __launch_bounds__(256) void linear_k(const float* __restrict__ x,
                                                const float* __restrict__ W,
                                                const float* __restrict__ b,
                                                float* __restrict__ y,
                                                __half* __restrict__ y16,
                                                const float* __restrict__ dinv, int n) {
    int lane = threadIdx.x & 63;
    int wid = blockIdx.x * (blockDim.x >> 6) + (threadIdx.x >> 6);
    int nwaves = gridDim.x * (blockDim.x >> 6);
    float wreg[K];
#pragma unroll
    for (int k = 0; k < K; ++k) wreg[k] = (lane < C) ? W[k * C + lane] : 0.0f;
    float bias = (BIAS_RELU && lane < C) ? b[lane] : 0.0f;
    for (int node = wid; node < n; node += nwaves) {
        float xv = (lane < K) ? x[(long)node * K + lane] : 0.0f;
        unsigned xu = __float_as_uint(xv);
        float a0 = 0.0f, a1 = 0.0f, a2 = 0.0f, a3 = 0.0f;
#pragma unroll
        for (int k = 0; k < K; k += 4) {
            a0 = fmaf(__uint_as_float(__builtin_amdgcn_readlane(xu, k + 0)), wreg[k + 0], a0);
            a1 = fmaf(__uint_as_float(__builtin_amdgcn_readlane(xu, k + 1)), wreg[k + 1], a1);
            a2 = fmaf(__uint_as_float(__builtin_amdgcn_readlane(xu, k + 2)), wreg[k + 2], a2);
            a3 = fmaf(__uint_as_float(__builtin_amdgcn_readlane(xu, k + 3)), wreg[k + 3], a3);
        }
        float acc = (a0 + a1) + (a2 + a3);
        if (BIAS_RELU) acc = fmaxf(acc + bias, 0.0f);
        if (lane < C) {
            y[(long)node * C + lane] = acc;
            if (DUAL16) y16[(long)node * 40 + lane] = __float2half(dinv[node] * acc);
        }
    }
}

// ---------------- gather at C=40: wave/node, lane=channel, stride-40 fp16 rows, 8-deep ----------------
// out = dinv[d] * sum(ew * feat16'[src]) + dinv[d]^2 * selfF[d] (+ b);  feat16' = dinv*feat
template <bool ADD_BIAS>
__global__ void gather40_k(const int* __restrict__ rowptr, const uint2* __restrict__ csr,
                           const __half* __restrict__ feat16, const float* __restrict__ selfF,
                           const float* __restrict__ dinv, const float* __restrict__ b,
                           float* __restrict__ out, int n) {
    int node = (int)(((long)blockIdx.x * blockDim.x + threadIdx.x) >> 6);
    int lane = threadIdx.x & 63;
    if (node >= n) return;
    int beg = __builtin_amdgcn_readfirstlane(rowptr[node]);
    int end = __builtin_amdgcn_readfirstlane(rowptr[node + 1]);
    if (lane >= 40) return;
    float accE = 0.0f;
    int t = beg;
    if (t < end && (t & 1)) {
        uint2 q = csr[t];
        accE = fmaf(__uint_as_float(q.y), __half2float(feat16[(long)q.x * 40 + lane]), accE);
        ++t;
    }
    for (; t + 7 < end; t += 8) {
        uint4 p0 = *reinterpret_cast<const uint4*>(csr + t);
        uint4 p1 = *reinterpret_cast<const uint4*>(csr + t + 2);
        uint4 p2 = *reinterpret_cast<const uint4*>(csr + t + 4);
        uint4 p3 = *reinterpret_cast<const uint4*>(csr + t + 6);
        float v0 = __half2float(feat16[(long)p0.x * 40 + lane]);
        float v1 = __half2float(feat16[(long)p0.z * 40 + lane]);
        float v2 = __half2float(feat16[(long)p1.x * 40 + lane]);
        float v3 = __half2float(feat16[(long)p1.z * 40 + lane]);
        float v4 = __half2float(feat16[(long)p2.x * 40 + lane]);
        float v5 = __half2float(feat16[(long)p2.z * 40 + lane]);
        float v6 = __half2float(feat16[(long)p3.x * 40 + lane]);
        float v7 = __half2float(feat16[(long)p3.z * 40 + lane]);
        accE = fmaf(__uint_as_float(p0.y), v0, accE);
        accE = fmaf(__uint_as_float(p0.w), v1, accE);
        accE = fmaf(__uint_as_float(p1.y), v2, accE);
        accE = fmaf(__uint_as_float(p1.w), v3, accE);
        accE = fmaf(__uint_as_float(p2.y), v4, accE);
        accE = fmaf(__uint_as_float(p2.w), v5, accE);
        accE = fmaf(__uint_as_float(p3.y), v6, accE);
        accE = fmaf(__uint_as_float(p3.w), v7, accE);
    }
    for (; t + 1 < end; t += 2) {
        uint4 p = *reinterpret_cast<const uint4*>(csr + t);
        float v0 = __half2float(feat16[(long)p.x * 40 + lane]);
        float v1 = __half2float(feat16[(long)p.z * 40 + lane]);
        accE = fmaf(__uint_as_float(p.y), v0, accE);
        accE = fmaf(__uint_as_float(p.w), v1, accE);
    }
    if (t < end) {
        uint2 q = csr[t];
        accE = fmaf(__uint_as_float(q.y), __half2float(feat16[(long)q.x * 40 + lane]), accE);
    }
    float di = dinv[node];
    float r = di * accE + di * di * selfF[(long)node * 40 + lane];
    if (ADD_BIAS) r += b[lane];
    out[(long)node * 40 + lane] = r;
}

extern "C" void kernel_launch(void* const* d_in, const int* in_sizes, int n_in,
                              void* d_out, int out_size, void* d_ws, size_t ws_size,
                              hipStream_t stream) {
    const float* x = (const float*)d_in[0];
    const int* ei = (const int*)d_in[1];
    const float* ew = (const float*)d_in[2];
    const float* W1 = (const float*)d_in[3];
    const float* b1 = (const float*)d_in[4];
    const float* W2 = (const float*)d_in[5];
    const float* b2 = (const float*)d_in[6];
    float* out = (float*)d_out;

    const int n = in_sizes[0] / 40;   // 100000
    const int e = in_sizes[2];        // 1600000
    const int* srcp = ei;
    const int* dstp = ei + e;
    const int NB = (n + CNODES - 1) >> CSH;  // 196 buckets
    const int M = NB * 8;                    // (bucket, class) streams

    // ws layout (4B units):
    // csr[2e] | tmp[2e] | dinv[n] | rowptr[n+1] | bbase[NB+1] | bcnt[M*16] | gcur[M*16] |
    // agg1/xl2_32[n*40] | h[n*64]
    // sh16 (40n halves = 20n words < 2e words) overlays tmp (dead after part2)
    uint2* csr = (uint2*)d_ws;
    ull* tmp = (ull*)(((int*)d_ws) + 2 * (long)e);
    float* dinv = (float*)(tmp + e);
    int* rowptr = (int*)(dinv + n);
    int* bbase = rowptr + n + 1;
    int* bcnt = bbase + NB + 1;
    int* gcur = bcnt + M * 16;
    float* agg1 = (float*)(gcur + M * 16);
    float* h = agg1 + (long)n * 40;
    float* xl2_32 = agg1;                 // overlay: agg1 dead after linear1
    __half* sh16 = (__half*)tmp;          // overlay: tmp dead after part2

    const int B = 256;
    auto cdiv = [](long a, long b) { return (int)((a + b - 1) / b); };
    const int egrid = cdiv(e, EB);

    // ---- CSR build (shared by both layers) ----
    zero_small_k<<<cdiv(M * 16, B), B, 0, stream>>>(bcnt, M * 16);
    bcount_k<<<egrid, B, 0, stream>>>(dstp, bcnt, e, NB);
    bscan_k<<<1, 64, 0, stream>>>(bcnt, bbase, gcur, NB, e);
    part1_k<<<egrid, B, 0, stream>>>(srcp, dstp, ew, gcur, tmp, e, NB);
    part2_k<<<NB, CNODES, 0, stream>>>(tmp, bbase, dinv, rowptr, csr, n, e, NB);

    // ---- x -> fp16 (dinv-folded, stride-40 rows) ----
    tohalf_k<<<cdiv((long)n * 5, B), B, 0, stream>>>(x, dinv, sh16, n);

    // ---- layer 1: agg1 = A_norm @ x, h = relu(agg1 @ W1 + b1) ----
    gather40_k<false><<<cdiv((long)n * 64, B), B, 0, stream>>>(rowptr, csr, sh16, x, dinv, nullptr, agg1, n);
    linear_k<40, 64, true, false><<<2048, B, 0, stream>>>(agg1, W1, b1, h, nullptr, nullptr, n);

    // ---- layer 2: xl2 = h @ W2 (f32 + dinv-folded fp16), out = A_norm @ xl2 + b2 ----
    linear_k<64, 40, false, true><<<2048, B, 0, stream>>>(h, W2, nullptr, xl2_32, sh16, dinv, n);
    gather40_k<true><<<cdiv((long)n * 64, B), B, 0, stream>>>(rowptr, csr, sh16, xl2_32, dinv, b2, out, n);
}

// Round 16
// 226.291 us; speedup vs baseline: 5.0944x; 1.2373x over previous
//
#include <hip/hip_runtime.h>
#include <hip/hip_fp16.h>

// fixed-point scale for weighted-degree accumulation (2^25)
#define FIX 33554432.0f
#define FIXINV (1.0f / 33554432.0f)

typedef unsigned long long ull;

#define EB 1024     // edges per block in bcount/part1 (identical grids => class counts match)
#define CSH 9       // bucket = 512 dst nodes
#define CNODES 512
#define MAXNB 256   // static LDS histogram capacity (NB=196 here)

// ---------------- tiny zero ----------------
__global__ void zero_small_k(int* p, int total) {
    int i = blockIdx.x * blockDim.x + threadIdx.x;
    if (i < total) p[i] = 0;
}

// ---------------- bucket histogram per XCD-class: LDS hist -> 1 atomic per (block,bucket) ----------------
__global__ void bcount_k(const int* __restrict__ dst, int* __restrict__ bcnt, int e, int NB) {
    __shared__ int lh[MAXNB];
    for (int i = threadIdx.x; i < NB; i += blockDim.x) lh[i] = 0;
    __syncthreads();
    int cls = blockIdx.x & 7;
    int base = blockIdx.x * EB + threadIdx.x * 4;
    if (base + 3 < e) {
        int4 d4 = *reinterpret_cast<const int4*>(dst + base);
        atomicAdd(&lh[d4.x >> CSH], 1);
        atomicAdd(&lh[d4.y >> CSH], 1);
        atomicAdd(&lh[d4.z >> CSH], 1);
        atomicAdd(&lh[d4.w >> CSH], 1);
    } else {
        for (int i = base; i < e && i < base + 4; ++i) atomicAdd(&lh[dst[i] >> CSH], 1);
    }
    __syncthreads();
    for (int i = threadIdx.x; i < NB; i += blockDim.x) {
        int c = lh[i];
        if (c) atomicAdd(&bcnt[(i * 8 + cls) * 16], c);
    }
}

// ---------------- parallel exclusive scan over M=(NB*8) padded counts -> cursors + bases ----------------
__global__ void bscan_k(const int* __restrict__ bcnt, int* __restrict__ bbase,
                        int* __restrict__ gcur, int M, int NB, int e) {
    __shared__ int lds[256];
    int per = (M + 255) / 256;
    int tid = threadIdx.x;
    int s = 0;
    for (int j = 0; j < per; ++j) {
        int idx = tid * per + j;
        if (idx < M) s += bcnt[idx * 16];
    }
    lds[tid] = s;
    __syncthreads();
    for (int off = 1; off < 256; off <<= 1) {
        int v = (tid >= off) ? lds[tid - off] : 0;
        __syncthreads();
        lds[tid] += v;
        __syncthreads();
    }
    int run = lds[tid] - s;  // exclusive prefix at this thread's first entry
    for (int j = 0; j < per; ++j) {
        int idx = tid * per + j;
        if (idx < M) {
            gcur[idx * 16] = run;
            if ((idx & 7) == 0) bbase[idx >> 3] = run;  // bucket base (class-minor order)
            run += bcnt[idx * 16];
        }
    }
    if (tid == 0) bbase[NB] = e;
}

// ---------------- phase 1: LDS-staged bucket partition, per-class cursors (XCD-local) ----------------
// rec = ewbits[57:26] | src[25:9] | (dst&511)[8:0]
__global__ void part1_k(const int* __restrict__ src, const int* __restrict__ dst,
                        const float* __restrict__ ew, int* gcur, ull* __restrict__ tmp,
                        int e, int NB) {
    __shared__ int lh[MAXNB];
    __shared__ int lb[MAXNB];
    for (int i = threadIdx.x; i < NB; i += blockDim.x) lh[i] = 0;
    __syncthreads();
    int cls = blockIdx.x & 7;
    int base = blockIdx.x * EB + threadIdx.x * 4;
    bool full = (blockIdx.x + 1) * EB <= e;  // block-uniform
    int bk[4], ls[4];
    ull rec[4];
    bool val[4];
    if (full) {
        int4 s4 = *reinterpret_cast<const int4*>(src + base);
        int4 d4 = *reinterpret_cast<const int4*>(dst + base);
        float4 e4 = *reinterpret_cast<const float4*>(ew + base);
        int s[4] = {s4.x, s4.y, s4.z, s4.w};
        int d[4] = {d4.x, d4.y, d4.z, d4.w};
        float ev[4] = {e4.x, e4.y, e4.z, e4.w};
#pragma unroll
        for (int j = 0; j < 4; ++j) {
            val[j] = true;
            bk[j] = d[j] >> CSH;
            rec[j] = ((ull)__float_as_uint(ev[j]) << 26) | ((ull)(unsigned)s[j] << 9) |
                     (ull)(unsigned)(d[j] & (CNODES - 1));
            ls[j] = atomicAdd(&lh[bk[j]], 1);
        }
    } else {
#pragma unroll
        for (int j = 0; j < 4; ++j) {
            int i = base + j;
            val[j] = (i < e);
            int s = val[j] ? src[i] : 0;
            int d = val[j] ? dst[i] : 0;
            float ev = val[j] ? ew[i] : 0.0f;
            bk[j] = d >> CSH;
            rec[j] = ((ull)__float_as_uint(ev) << 26) | ((ull)(unsigned)s << 9) |
                     (ull)(unsigned)(d & (CNODES - 1));
            ls[j] = val[j] ? atomicAdd(&lh[bk[j]], 1) : 0;
        }
    }
    __syncthreads();
    for (int i = threadIdx.x; i < NB; i += blockDim.x) {
        int c = lh[i];
        lb[i] = c ? atomicAdd(&gcur[(i * 8 + cls) * 16], c) : 0;
    }
    __syncthreads();
#pragma unroll
    for (int j = 0; j < 4; ++j)
        if (val[j]) tmp[lb[bk[j]] + ls[j]] = rec[j];
}

// ---------------- phase 2: per-bucket cnt/deg/dinv/rowptr + node-sorted CSR ----------------
__global__ __launch_bounds__(CNODES) void part2_k(const ull* __restrict__ tmp,
                                                  const int* __restrict__ bbase,
                                                  float* __restrict__ dinv,
                                                  int* __restrict__ rowptr,
                                                  uint2* __restrict__ csr,
                                                  int n, int e, int NB) {
    __shared__ ull ldc[CNODES];   // hi32: cnt, lo32: fixed-point deg
    __shared__ int sc[CNODES];    // scan buffer, then global cursor
    int b = blockIdx.x;
    int tid = threadIdx.x;
    ldc[tid] = 0;
    __syncthreads();
    int beg = bbase[b], end = bbase[b + 1];
    // pass A: count + weighted degree (deterministic fixed-point)
    for (int i = beg + tid; i < end; i += CNODES) {
        ull rec = tmp[i];
        int dlo = (int)(rec & (CNODES - 1));
        float ewv = __uint_as_float((unsigned)(rec >> 26));
        atomicAdd(&ldc[dlo], (1ULL << 32) | (ull)__float2uint_rn(ewv * FIX));
    }
    __syncthreads();
    ull v = ldc[tid];
    int cnt = (int)(v >> 32);
    int node = b * CNODES + tid;
    if (node < n) {
        float d = (float)(unsigned)((unsigned)(v & 0xffffffffu) + (1u << 25)) * FIXINV;
        dinv[node] = rsqrtf(d);  // d >= 1 always
    }
    // inclusive scan of cnt over CNODES threads (Hillis-Steele)
    sc[tid] = cnt;
    __syncthreads();
    for (int off = 1; off < CNODES; off <<= 1) {
        int x = (tid >= off) ? sc[tid - off] : 0;
        __syncthreads();
        sc[tid] += x;
        __syncthreads();
    }
    int slotbase = beg + sc[tid] - cnt;  // global CSR base for this node
    if (node < n) rowptr[node] = slotbase;
    if (b == NB - 1 && tid == 0) rowptr[n] = e;
    __syncthreads();
    sc[tid] = slotbase;  // reuse as cursor
    __syncthreads();
    // pass B: scatter into node-sorted CSR (records L2-resident from pass A)
    for (int i = beg + tid; i < end; i += CNODES) {
        ull rec = tmp[i];
        int dlo = (int)(rec & (CNODES - 1));
        unsigned s = (unsigned)((rec >> 9) & 0x1FFFF);
        unsigned ewb = (unsigned)(rec >> 26);
        int slot = atomicAdd(&sc[dlo], 1);
        csr[slot] = make_uint2(s, ewb);
    }
}

// ---------------- x -> fp16 rows at stride 40 (80B rows, 16B-aligned), dinv-folded ----------------
__global__ void tohalf_k(const float* __restrict__ x, const float* __restrict__ dinv,
                         __half* __restrict__ out, int n) {
    long gid = (long)blockIdx.x * blockDim.x + threadIdx.x;
    if (gid >= (long)n * 5) return;
    int row = (int)(gid / 5), c = (int)(gid % 5);
    float di = dinv[row];
    const float4* src = reinterpret_cast<const float4*>(x + (long)row * 40 + c * 8);
    float4 a = src[0], bb = src[1];
    __half2* dst = reinterpret_cast<__half2*>(out + (long)row * 40 + c * 8);
    dst[0] = __floats2half2_rn(di * a.x, di * a.y);
    dst[1] = __floats2half2_rn(di * a.z, di * a.w);
    dst[2] = __floats2half2_rn(di * bb.x, di * bb.y);
    dst[3] = __floats2half2_rn(di * bb.z, di * bb.w);
}

// ---------------- dense linear, wave-per-node: W in VGPRs, coalesced row + readlane ----------------
template <int K, int C, bool BIAS_RELU, bool DUAL16>
__global__ __launch_bounds__(256) void linear_k(const float* __restrict__ x,
                                                const float* __restrict__ W,
                                                const float* __restrict__ b,
                                                float* __restrict__ y,
                                                __half* __restrict__ y16,
                                                const float* __restrict__ dinv, int n) {
    int lane = threadIdx.x & 63;
    int wid = blockIdx.x * (blockDim.x >> 6) + (threadIdx.x >> 6);
    int nwaves = gridDim.x * (blockDim.x >> 6);
    float wreg[K];
#pragma unroll
    for (int k = 0; k < K; ++k) wreg[k] = (lane < C) ? W[k * C + lane] : 0.0f;
    float bias = (BIAS_RELU && lane < C) ? b[lane] : 0.0f;
    for (int node = wid; node < n; node += nwaves) {
        float xv = (lane < K) ? x[(long)node * K + lane] : 0.0f;
        unsigned xu = __float_as_uint(xv);
        float a0 = 0.0f, a1 = 0.0f, a2 = 0.0f, a3 = 0.0f;
#pragma unroll
        for (int k = 0; k < K; k += 4) {
            a0 = fmaf(__uint_as_float(__builtin_amdgcn_readlane(xu, k + 0)), wreg[k + 0], a0);
            a1 = fmaf(__uint_as_float(__builtin_amdgcn_readlane(xu, k + 1)), wreg[k + 1], a1);
            a2 = fmaf(__uint_as_float(__builtin_amdgcn_readlane(xu, k + 2)), wreg[k + 2], a2);
            a3 = fmaf(__uint_as_float(__builtin_amdgcn_readlane(xu, k + 3)), wreg[k + 3], a3);
        }
        float acc = (a0 + a1) + (a2 + a3);
        if (BIAS_RELU) acc = fmaxf(acc + bias, 0.0f);
        if (lane < C) {
            y[(long)node * C + lane] = acc;
            if (DUAL16) y16[(long)node * 40 + lane] = __float2half(dinv[node] * acc);
        }
    }
}

// ---------------- gather at C=40: wave/node, lane=channel, stride-40 fp16 rows, 8-deep ----------------
// out = dinv[d] * sum(ew * feat16'[src]) + dinv[d]^2 * selfF[d] (+ b);  feat16' = dinv*feat
template <bool ADD_BIAS>
__global__ void gather40_k(const int* __restrict__ rowptr, const uint2* __restrict__ csr,
                           const __half* __restrict__ feat16, const float* __restrict__ selfF,
                           const float* __restrict__ dinv, const float* __restrict__ b,
                           float* __restrict__ out, int n) {
    int node = (int)(((long)blockIdx.x * blockDim.x + threadIdx.x) >> 6);
    int lane = threadIdx.x & 63;
    if (node >= n) return;
    int beg = __builtin_amdgcn_readfirstlane(rowptr[node]);
    int end = __builtin_amdgcn_readfirstlane(rowptr[node + 1]);
    if (lane >= 40) return;
    float accE = 0.0f;
    int t = beg;
    if (t < end && (t & 1)) {
        uint2 q = csr[t];
        accE = fmaf(__uint_as_float(q.y), __half2float(feat16[(long)q.x * 40 + lane]), accE);
        ++t;
    }
    for (; t + 7 < end; t += 8) {
        uint4 p0 = *reinterpret_cast<const uint4*>(csr + t);
        uint4 p1 = *reinterpret_cast<const uint4*>(csr + t + 2);
        uint4 p2 = *reinterpret_cast<const uint4*>(csr + t + 4);
        uint4 p3 = *reinterpret_cast<const uint4*>(csr + t + 6);
        float v0 = __half2float(feat16[(long)p0.x * 40 + lane]);
        float v1 = __half2float(feat16[(long)p0.z * 40 + lane]);
        float v2 = __half2float(feat16[(long)p1.x * 40 + lane]);
        float v3 = __half2float(feat16[(long)p1.z * 40 + lane]);
        float v4 = __half2float(feat16[(long)p2.x * 40 + lane]);
        float v5 = __half2float(feat16[(long)p2.z * 40 + lane]);
        float v6 = __half2float(feat16[(long)p3.x * 40 + lane]);
        float v7 = __half2float(feat16[(long)p3.z * 40 + lane]);
        accE = fmaf(__uint_as_float(p0.y), v0, accE);
        accE = fmaf(__uint_as_float(p0.w), v1, accE);
        accE = fmaf(__uint_as_float(p1.y), v2, accE);
        accE = fmaf(__uint_as_float(p1.w), v3, accE);
        accE = fmaf(__uint_as_float(p2.y), v4, accE);
        accE = fmaf(__uint_as_float(p2.w), v5, accE);
        accE = fmaf(__uint_as_float(p3.y), v6, accE);
        accE = fmaf(__uint_as_float(p3.w), v7, accE);
    }
    for (; t + 1 < end; t += 2) {
        uint4 p = *reinterpret_cast<const uint4*>(csr + t);
        float v0 = __half2float(feat16[(long)p.x * 40 + lane]);
        float v1 = __half2float(feat16[(long)p.z * 40 + lane]);
        accE = fmaf(__uint_as_float(p.y), v0, accE);
        accE = fmaf(__uint_as_float(p.w), v1, accE);
    }
    if (t < end) {
        uint2 q = csr[t];
        accE = fmaf(__uint_as_float(q.y), __half2float(feat16[(long)q.x * 40 + lane]), accE);
    }
    float di = dinv[node];
    float r = di * accE + di * di * selfF[(long)node * 40 + lane];
    if (ADD_BIAS) r += b[lane];
    out[(long)node * 40 + lane] = r;
}

extern "C" void kernel_launch(void* const* d_in, const int* in_sizes, int n_in,
                              void* d_out, int out_size, void* d_ws, size_t ws_size,
                              hipStream_t stream) {
    const float* x = (const float*)d_in[0];
    const int* ei = (const int*)d_in[1];
    const float* ew = (const float*)d_in[2];
    const float* W1 = (const float*)d_in[3];
    const float* b1 = (const float*)d_in[4];
    const float* W2 = (const float*)d_in[5];
    const float* b2 = (const float*)d_in[6];
    float* out = (float*)d_out;

    const int n = in_sizes[0] / 40;   // 100000
    const int e = in_sizes[2];        // 1600000
    const int* srcp = ei;
    const int* dstp = ei + e;
    const int NB = (n + CNODES - 1) >> CSH;  // 196 buckets
    const int M = NB * 8;                    // (bucket, class) streams

    // ws layout (4B units):
    // csr[2e] | tmp[2e] | dinv[n] | rowptr[n+1] | bbase[NB+1] | bcnt[M*16] | gcur[M*16] |
    // agg1/xl2_32[n*40] | h[n*64]
    // sh16 (40n halves = 20n words < 2e words) overlays tmp (dead after part2)
    uint2* csr = (uint2*)d_ws;
    ull* tmp = (ull*)(((int*)d_ws) + 2 * (long)e);
    float* dinv = (float*)(tmp + e);
    int* rowptr = (int*)(dinv + n);
    int* bbase = rowptr + n + 1;
    int* bcnt = bbase + NB + 1;
    int* gcur = bcnt + M * 16;
    float* agg1 = (float*)(gcur + M * 16);
    float* h = agg1 + (long)n * 40;
    float* xl2_32 = agg1;                 // overlay: agg1 dead after linear1
    __half* sh16 = (__half*)tmp;          // overlay: tmp dead after part2

    const int B = 256;
    auto cdiv = [](long a, long b) { return (int)((a + b - 1) / b); };
    const int egrid = cdiv(e, EB);

    // ---- CSR build (shared by both layers) ----
    zero_small_k<<<cdiv(M * 16, B), B, 0, stream>>>(bcnt, M * 16);
    bcount_k<<<egrid, B, 0, stream>>>(dstp, bcnt, e, NB);
    bscan_k<<<1, 256, 0, stream>>>(bcnt, bbase, gcur, M, NB, e);
    part1_k<<<egrid, B, 0, stream>>>(srcp, dstp, ew, gcur, tmp, e, NB);
    part2_k<<<NB, CNODES, 0, stream>>>(tmp, bbase, dinv, rowptr, csr, n, e, NB);

    // ---- x -> fp16 (dinv-folded, stride-40 rows) ----
    tohalf_k<<<cdiv((long)n * 5, B), B, 0, stream>>>(x, dinv, sh16, n);

    // ---- layer 1: agg1 = A_norm @ x, h = relu(agg1 @ W1 + b1) ----
    gather40_k<false><<<cdiv((long)n * 64, B), B, 0, stream>>>(rowptr, csr, sh16, x, dinv, nullptr, agg1, n);
    linear_k<40, 64, true, false><<<2048, B, 0, stream>>>(agg1, W1, b1, h, nullptr, nullptr, n);

    // ---- layer 2: xl2 = h @ W2 (f32 + dinv-folded fp16), out = A_norm @ xl2 + b2 ----
    linear_k<64, 40, false, true><<<2048, B, 0, stream>>>(h, W2, nullptr, xl2_32, sh16, dinv, n);
    gather40_k<true><<<cdiv((long)n * 64, B), B, 0, stream>>>(rowptr, csr, sh16, xl2_32, dinv, b2, out, n);
}

// Round 17
// 218.454 us; speedup vs baseline: 5.2772x; 1.0359x over previous
//
#include <hip/hip_runtime.h>
#include <hip/hip_fp16.h>

// fixed-point scale for weighted-degree accumulation (2^25)
#define FIX 33554432.0f
#define FIXINV (1.0f / 33554432.0f)

typedef unsigned long long ull;

#define EB 1024     // edges per block in bcount/part1 (identical grids => class counts match)
#define CSH 9       // bucket = 512 dst nodes
#define CNODES 512
#define MAXNB 256   // static LDS histogram capacity (NB=196 here)

// ---------------- tiny zero ----------------
__global__ void zero_small_k(int* p, int total) {
    int i = blockIdx.x * blockDim.x + threadIdx.x;
    if (i < total) p[i] = 0;
}

// ---------------- bucket histogram per XCD-class: LDS hist -> 1 atomic per (block,bucket) ----------------
__global__ void bcount_k(const int* __restrict__ dst, int* __restrict__ bcnt, int e, int NB) {
    __shared__ int lh[MAXNB];
    for (int i = threadIdx.x; i < NB; i += blockDim.x) lh[i] = 0;
    __syncthreads();
    int cls = blockIdx.x & 7;
    int base = blockIdx.x * EB + threadIdx.x * 4;
    if (base + 3 < e) {
        int4 d4 = *reinterpret_cast<const int4*>(dst + base);
        atomicAdd(&lh[d4.x >> CSH], 1);
        atomicAdd(&lh[d4.y >> CSH], 1);
        atomicAdd(&lh[d4.z >> CSH], 1);
        atomicAdd(&lh[d4.w >> CSH], 1);
    } else {
        for (int i = base; i < e && i < base + 4; ++i) atomicAdd(&lh[dst[i] >> CSH], 1);
    }
    __syncthreads();
    for (int i = threadIdx.x; i < NB; i += blockDim.x) {
        int c = lh[i];
        if (c) atomicAdd(&bcnt[(i * 8 + cls) * 16], c);
    }
}

// ---------------- parallel exclusive scan over M=(NB*8) padded counts -> cursors + bases ----------------
__global__ void bscan_k(const int* __restrict__ bcnt, int* __restrict__ bbase,
                        int* __restrict__ gcur, int M, int NB, int e) {
    __shared__ int lds[256];
    int per = (M + 255) / 256;
    int tid = threadIdx.x;
    int s = 0;
    for (int j = 0; j < per; ++j) {
        int idx = tid * per + j;
        if (idx < M) s += bcnt[idx * 16];
    }
    lds[tid] = s;
    __syncthreads();
    for (int off = 1; off < 256; off <<= 1) {
        int v = (tid >= off) ? lds[tid - off] : 0;
        __syncthreads();
        lds[tid] += v;
        __syncthreads();
    }
    int run = lds[tid] - s;  // exclusive prefix at this thread's first entry
    for (int j = 0; j < per; ++j) {
        int idx = tid * per + j;
        if (idx < M) {
            gcur[idx * 16] = run;
            if ((idx & 7) == 0) bbase[idx >> 3] = run;  // bucket base (class-minor order)
            run += bcnt[idx * 16];
        }
    }
    if (tid == 0) bbase[NB] = e;
}

// ---------------- phase 1: LDS-staged bucket partition, per-class cursors (XCD-local) ----------------
// rec = ewbits[57:26] | src[25:9] | (dst&511)[8:0]
__global__ void part1_k(const int* __restrict__ src, const int* __restrict__ dst,
                        const float* __restrict__ ew, int* gcur, ull* __restrict__ tmp,
                        int e, int NB) {
    __shared__ int lh[MAXNB];
    __shared__ int lb[MAXNB];
    for (int i = threadIdx.x; i < NB; i += blockDim.x) lh[i] = 0;
    __syncthreads();
    int cls = blockIdx.x & 7;
    int base = blockIdx.x * EB + threadIdx.x * 4;
    bool full = (blockIdx.x + 1) * EB <= e;  // block-uniform
    int bk[4], ls[4];
    ull rec[4];
    bool val[4];
    if (full) {
        int4 s4 = *reinterpret_cast<const int4*>(src + base);
        int4 d4 = *reinterpret_cast<const int4*>(dst + base);
        float4 e4 = *reinterpret_cast<const float4*>(ew + base);
        int s[4] = {s4.x, s4.y, s4.z, s4.w};
        int d[4] = {d4.x, d4.y, d4.z, d4.w};
        float ev[4] = {e4.x, e4.y, e4.z, e4.w};
#pragma unroll
        for (int j = 0; j < 4; ++j) {
            val[j] = true;
            bk[j] = d[j] >> CSH;
            rec[j] = ((ull)__float_as_uint(ev[j]) << 26) | ((ull)(unsigned)s[j] << 9) |
                     (ull)(unsigned)(d[j] & (CNODES - 1));
            ls[j] = atomicAdd(&lh[bk[j]], 1);
        }
    } else {
#pragma unroll
        for (int j = 0; j < 4; ++j) {
            int i = base + j;
            val[j] = (i < e);
            int s = val[j] ? src[i] : 0;
            int d = val[j] ? dst[i] : 0;
            float ev = val[j] ? ew[i] : 0.0f;
            bk[j] = d >> CSH;
            rec[j] = ((ull)__float_as_uint(ev) << 26) | ((ull)(unsigned)s << 9) |
                     (ull)(unsigned)(d & (CNODES - 1));
            ls[j] = val[j] ? atomicAdd(&lh[bk[j]], 1) : 0;
        }
    }
    __syncthreads();
    for (int i = threadIdx.x; i < NB; i += blockDim.x) {
        int c = lh[i];
        lb[i] = c ? atomicAdd(&gcur[(i * 8 + cls) * 16], c) : 0;
    }
    __syncthreads();
#pragma unroll
    for (int j = 0; j < 4; ++j)
        if (val[j]) tmp[lb[bk[j]] + ls[j]] = rec[j];
}

// ---------------- phase 2: per-bucket cnt/deg/dinv/rowptr + node-sorted CSR ----------------
__global__ __launch_bounds__(CNODES) void part2_k(const ull* __restrict__ tmp,
                                                  const int* __restrict__ bbase,
                                                  float* __restrict__ dinv,
                                                  int* __restrict__ rowptr,
                                                  uint2* __restrict__ csr,
                                                  int n, int e, int NB) {
    __shared__ ull ldc[CNODES];   // hi32: cnt, lo32: fixed-point deg
    __shared__ int sc[CNODES];    // scan buffer, then global cursor
    int b = blockIdx.x;
    int tid = threadIdx.x;
    ldc[tid] = 0;
    __syncthreads();
    int beg = bbase[b], end = bbase[b + 1];
    // pass A: count + weighted degree (deterministic fixed-point)
    for (int i = beg + tid; i < end; i += CNODES) {
        ull rec = tmp[i];
        int dlo = (int)(rec & (CNODES - 1));
        float ewv = __uint_as_float((unsigned)(rec >> 26));
        atomicAdd(&ldc[dlo], (1ULL << 32) | (ull)__float2uint_rn(ewv * FIX));
    }
    __syncthreads();
    ull v = ldc[tid];
    int cnt = (int)(v >> 32);
    int node = b * CNODES + tid;
    if (node < n) {
        float d = (float)(unsigned)((unsigned)(v & 0xffffffffu) + (1u << 25)) * FIXINV;
        dinv[node] = rsqrtf(d);  // d >= 1 always
    }
    // inclusive scan of cnt over CNODES threads (Hillis-Steele)
    sc[tid] = cnt;
    __syncthreads();
    for (int off = 1; off < CNODES; off <<= 1) {
        int x = (tid >= off) ? sc[tid - off] : 0;
        __syncthreads();
        sc[tid] += x;
        __syncthreads();
    }
    int slotbase = beg + sc[tid] - cnt;  // global CSR base for this node
    if (node < n) rowptr[node] = slotbase;
    if (b == NB - 1 && tid == 0) rowptr[n] = e;
    __syncthreads();
    sc[tid] = slotbase;  // reuse as cursor
    __syncthreads();
    // pass B: scatter into node-sorted CSR (records L2-resident from pass A)
    for (int i = beg + tid; i < end; i += CNODES) {
        ull rec = tmp[i];
        int dlo = (int)(rec & (CNODES - 1));
        unsigned s = (unsigned)((rec >> 9) & 0x1FFFF);
        unsigned ewb = (unsigned)(rec >> 26);
        int slot = atomicAdd(&sc[dlo], 1);
        csr[slot] = make_uint2(s, ewb);
    }
}

// ---------------- x -> fp16 rows at stride 40 (80B rows, 16B-aligned), dinv-folded ----------------
__global__ void tohalf_k(const float* __restrict__ x, const float* __restrict__ dinv,
                         __half* __restrict__ out, int n) {
    long gid = (long)blockIdx.x * blockDim.x + threadIdx.x;
    if (gid >= (long)n * 5) return;
    int row = (int)(gid / 5), c = (int)(gid % 5);
    float di = dinv[row];
    const float4* src = reinterpret_cast<const float4*>(x + (long)row * 40 + c * 8);
    float4 a = src[0], bb = src[1];
    __half2* dst = reinterpret_cast<__half2*>(out + (long)row * 40 + c * 8);
    dst[0] = __floats2half2_rn(di * a.x, di * a.y);
    dst[1] = __floats2half2_rn(di * a.z, di * a.w);
    dst[2] = __floats2half2_rn(di * bb.x, di * bb.y);
    dst[3] = __floats2half2_rn(di * bb.z, di * bb.w);
}

// ---------------- edge-gather core: accE = sum(ew * feat16[src][ln]), 8-deep, uint4 csr ----------------
__device__ __forceinline__ float gather_core(const uint2* __restrict__ csr,
                                             const __half* __restrict__ feat16,
                                             int beg, int end, int ln) {
    float accE = 0.0f;
    int t = beg;
    if (t < end && (t & 1)) {
        uint2 q = csr[t];
        accE = fmaf(__uint_as_float(q.y), __half2float(feat16[(long)q.x * 40 + ln]), accE);
        ++t;
    }
    for (; t + 7 < end; t += 8) {
        uint4 p0 = *reinterpret_cast<const uint4*>(csr + t);
        uint4 p1 = *reinterpret_cast<const uint4*>(csr + t + 2);
        uint4 p2 = *reinterpret_cast<const uint4*>(csr + t + 4);
        uint4 p3 = *reinterpret_cast<const uint4*>(csr + t + 6);
        float v0 = __half2float(feat16[(long)p0.x * 40 + ln]);
        float v1 = __half2float(feat16[(long)p0.z * 40 + ln]);
        float v2 = __half2float(feat16[(long)p1.x * 40 + ln]);
        float v3 = __half2float(feat16[(long)p1.z * 40 + ln]);
        float v4 = __half2float(feat16[(long)p2.x * 40 + ln]);
        float v5 = __half2float(feat16[(long)p2.z * 40 + ln]);
        float v6 = __half2float(feat16[(long)p3.x * 40 + ln]);
        float v7 = __half2float(feat16[(long)p3.z * 40 + ln]);
        accE = fmaf(__uint_as_float(p0.y), v0, accE);
        accE = fmaf(__uint_as_float(p0.w), v1, accE);
        accE = fmaf(__uint_as_float(p1.y), v2, accE);
        accE = fmaf(__uint_as_float(p1.w), v3, accE);
        accE = fmaf(__uint_as_float(p2.y), v4, accE);
        accE = fmaf(__uint_as_float(p2.w), v5, accE);
        accE = fmaf(__uint_as_float(p3.y), v6, accE);
        accE = fmaf(__uint_as_float(p3.w), v7, accE);
    }
    for (; t + 1 < end; t += 2) {
        uint4 p = *reinterpret_cast<const uint4*>(csr + t);
        float v0 = __half2float(feat16[(long)p.x * 40 + ln]);
        float v1 = __half2float(feat16[(long)p.z * 40 + ln]);
        accE = fmaf(__uint_as_float(p.y), v0, accE);
        accE = fmaf(__uint_as_float(p.w), v1, accE);
    }
    if (t < end) {
        uint2 q = csr[t];
        accE = fmaf(__uint_as_float(q.y), __half2float(feat16[(long)q.x * 40 + ln]), accE);
    }
    return accE;
}

// ---------------- FUSED layer 1: gather (C=40) + linear1 (K=40 -> C=64) + ReLU ----------------
// agg[lane<40] = di*(accE + feat16[node]);  h[node][lane<64] = relu(sum_k readlane(agg,k)*W1[k][lane] + b1)
__global__ __launch_bounds__(256) void gatherlin_k(const int* __restrict__ rowptr,
                                                   const uint2* __restrict__ csr,
                                                   const __half* __restrict__ feat16,
                                                   const float* __restrict__ dinv,
                                                   const float* __restrict__ W1,
                                                   const float* __restrict__ b1,
                                                   float* __restrict__ h, int n) {
    int lane = threadIdx.x & 63;
    int wid = blockIdx.x * (blockDim.x >> 6) + (threadIdx.x >> 6);
    int nwaves = gridDim.x * (blockDim.x >> 6);
    float w1reg[40];
#pragma unroll
    for (int k = 0; k < 40; ++k) w1reg[k] = W1[k * 64 + lane];  // C=64: all lanes valid
    float b1v = b1[lane];
    int ln = (lane < 40) ? lane : 0;  // clamp: lanes 40-63 re-read lane0's bytes (same lines)
    for (int node = wid; node < n; node += nwaves) {
        int beg = __builtin_amdgcn_readfirstlane(rowptr[node]);
        int end = __builtin_amdgcn_readfirstlane(rowptr[node + 1]);
        float accE = gather_core(csr, feat16, beg, end, ln);
        float selfv = __half2float(feat16[(long)node * 40 + ln]);
        float di = dinv[node];
        unsigned aggu = __float_as_uint(di * (accE + selfv));
        float a0 = 0.0f, a1 = 0.0f, a2 = 0.0f, a3 = 0.0f;
#pragma unroll
        for (int k = 0; k < 40; k += 4) {
            a0 = fmaf(__uint_as_float(__builtin_amdgcn_readlane(aggu, k + 0)), w1reg[k + 0], a0);
            a1 = fmaf(__uint_as_float(__builtin_amdgcn_readlane(aggu, k + 1)), w1reg[k + 1], a1);
            a2 = fmaf(__uint_as_float(__builtin_amdgcn_readlane(aggu, k + 2)), w1reg[k + 2], a2);
            a3 = fmaf(__uint_as_float(__builtin_amdgcn_readlane(aggu, k + 3)), w1reg[k + 3], a3);
        }
        float hv = fmaxf((a0 + a1) + (a2 + a3) + b1v, 0.0f);
        h[(long)node * 64 + lane] = hv;
    }
}

// ---------------- linear 2: xl2_16 = half(dinv * (h @ W2)), fp16 output ONLY ----------------
__global__ __launch_bounds__(256) void linear2_k(const float* __restrict__ h,
                                                 const float* __restrict__ W2,
                                                 __half* __restrict__ y16,
                                                 const float* __restrict__ dinv, int n) {
    int lane = threadIdx.x & 63;
    int wid = blockIdx.x * (blockDim.x >> 6) + (threadIdx.x >> 6);
    int nwaves = gridDim.x * (blockDim.x >> 6);
    float wreg[64];
#pragma unroll
    for (int k = 0; k < 64; ++k) wreg[k] = (lane < 40) ? W2[k * 40 + lane] : 0.0f;
    for (int node = wid; node < n; node += nwaves) {
        float xv = h[(long)node * 64 + lane];  // K=64: all lanes load
        unsigned xu = __float_as_uint(xv);
        float a0 = 0.0f, a1 = 0.0f, a2 = 0.0f, a3 = 0.0f;
#pragma unroll
        for (int k = 0; k < 64; k += 4) {
            a0 = fmaf(__uint_as_float(__builtin_amdgcn_readlane(xu, k + 0)), wreg[k + 0], a0);
            a1 = fmaf(__uint_as_float(__builtin_amdgcn_readlane(xu, k + 1)), wreg[k + 1], a1);
            a2 = fmaf(__uint_as_float(__builtin_amdgcn_readlane(xu, k + 2)), wreg[k + 2], a2);
            a3 = fmaf(__uint_as_float(__builtin_amdgcn_readlane(xu, k + 3)), wreg[k + 3], a3);
        }
        float acc = (a0 + a1) + (a2 + a3);
        if (lane < 40) y16[(long)node * 40 + lane] = __float2half(dinv[node] * acc);
    }
}

// ---------------- final gather at C=40: self term from fp16 table, +bias ----------------
// out = dinv[d] * (sum(ew * feat16[src]) + feat16[d]) + b
__global__ void gather40_k(const int* __restrict__ rowptr, const uint2* __restrict__ csr,
                           const __half* __restrict__ feat16, const float* __restrict__ dinv,
                           const float* __restrict__ b, float* __restrict__ out, int n) {
    int node = (int)(((long)blockIdx.x * blockDim.x + threadIdx.x) >> 6);
    int lane = threadIdx.x & 63;
    if (node >= n) return;
    int beg = __builtin_amdgcn_readfirstlane(rowptr[node]);
    int end = __builtin_amdgcn_readfirstlane(rowptr[node + 1]);
    if (lane >= 40) return;
    float accE = gather_core(csr, feat16, beg, end, lane);
    float selfv = __half2float(feat16[(long)node * 40 + lane]);
    float di = dinv[node];
    out[(long)node * 40 + lane] = di * (accE + selfv) + b[lane];
}

extern "C" void kernel_launch(void* const* d_in, const int* in_sizes, int n_in,
                              void* d_out, int out_size, void* d_ws, size_t ws_size,
                              hipStream_t stream) {
    const float* x = (const float*)d_in[0];
    const int* ei = (const int*)d_in[1];
    const float* ew = (const float*)d_in[2];
    const float* W1 = (const float*)d_in[3];
    const float* b1 = (const float*)d_in[4];
    const float* W2 = (const float*)d_in[5];
    const float* b2 = (const float*)d_in[6];
    float* out = (float*)d_out;

    const int n = in_sizes[0] / 40;   // 100000
    const int e = in_sizes[2];        // 1600000
    const int* srcp = ei;
    const int* dstp = ei + e;
    const int NB = (n + CNODES - 1) >> CSH;  // 196 buckets
    const int M = NB * 8;                    // (bucket, class) streams

    // ws layout (4B units):
    // csr[2e] | tmp[2e] | dinv[n] | rowptr[n+1] | bbase[NB+1] | bcnt[M*16] | gcur[M*16] |
    // h[n*64] | xl2_16 (40n halves = 20n words)
    // sh16 (40n halves = 20n words < 2e words) overlays tmp (dead after part2)
    uint2* csr = (uint2*)d_ws;
    ull* tmp = (ull*)(((int*)d_ws) + 2 * (long)e);
    float* dinv = (float*)(tmp + e);
    int* rowptr = (int*)(dinv + n);
    int* bbase = rowptr + n + 1;
    int* bcnt = bbase + NB + 1;
    int* gcur = bcnt + M * 16;
    float* h = (float*)(gcur + M * 16);
    __half* xl2_16 = (__half*)(h + (long)n * 64);
    __half* sh16 = (__half*)tmp;          // overlay: tmp dead after part2

    const int B = 256;
    auto cdiv = [](long a, long b) { return (int)((a + b - 1) / b); };
    const int egrid = cdiv(e, EB);

    // ---- CSR build (shared by both layers) ----
    zero_small_k<<<cdiv(M * 16, B), B, 0, stream>>>(bcnt, M * 16);
    bcount_k<<<egrid, B, 0, stream>>>(dstp, bcnt, e, NB);
    bscan_k<<<1, 256, 0, stream>>>(bcnt, bbase, gcur, M, NB, e);
    part1_k<<<egrid, B, 0, stream>>>(srcp, dstp, ew, gcur, tmp, e, NB);
    part2_k<<<NB, CNODES, 0, stream>>>(tmp, bbase, dinv, rowptr, csr, n, e, NB);

    // ---- x -> fp16 (dinv-folded, stride-40 rows) ----
    tohalf_k<<<cdiv((long)n * 5, B), B, 0, stream>>>(x, dinv, sh16, n);

    // ---- layer 1 fused: h = relu((A_norm @ x) @ W1 + b1) ----
    gatherlin_k<<<4096, B, 0, stream>>>(rowptr, csr, sh16, dinv, W1, b1, h, n);

    // ---- layer 2: xl2_16 = half(dinv * (h @ W2)); out = A_norm-gather + b2 ----
    linear2_k<<<2048, B, 0, stream>>>(h, W2, xl2_16, dinv, n);
    gather40_k<<<cdiv((long)n * 64, B), B, 0, stream>>>(rowptr, csr, xl2_16, dinv, b2, out, n);
}